// Round 13
// baseline (63.403 us; speedup 1.0000x reference)
//
#include <hip/hip_runtime.h>
#include <hip/hip_bf16.h>
#include <math.h>

#define B_  2
#define N_  6
#define D_  128
#define Q_  2500
#define HK  420
#define NK  2520
#define NKP 2560      // padded keys (40 zero-pads)
#define M_  4
#define DH  32
#define SPLIT 16
#define KPSP 160      // NKP/SPLIT
#define CHUNKS 5      // KPSP/32
#define SCALE 0.25503487775f   // 32^-0.5 * log2(e); attn uses exp2

typedef __attribute__((ext_vector_type(8))) short short8v;
typedef __attribute__((ext_vector_type(4))) float f32x4;
typedef __attribute__((ext_vector_type(2))) unsigned u32x2;
typedef __attribute__((ext_vector_type(4))) unsigned u32x4;

__device__ __forceinline__ unsigned short f2b(float x) {
  unsigned u = __float_as_uint(x);
  return (unsigned short)((u + 0x7FFFu + ((u >> 16) & 1u)) >> 16);
}

__device__ __forceinline__ unsigned pk2(float lo, float hi) {
  return (unsigned)f2b(lo) | ((unsigned)f2b(hi) << 16);
}

__device__ __forceinline__ float bl(unsigned u) { return __uint_as_float(u << 16); }
__device__ __forceinline__ float bh(unsigned u) { return __uint_as_float(u & 0xffff0000u); }

// K-chunk storage permutation: actual key a (0..31) -> buffer position p so that
// the QK^T D-layout lands P[8g+e] directly in lane (q16,g)'s PV B-frag slots.
__device__ __forceinline__ int kperm(int a) {
  const int h = a & 7;
  return ((h >= 4) ? 16 : 0) + 4 * (a >> 3) + (h & 3);
}

// ---------------- Kernel 1: prepack weights to MFMA B-frag order + zero pad chunks ----------------
__global__ __launch_bounds__(256)
void setup_kernel(const float* __restrict__ wp, const float* __restrict__ w1,
                  const float* __restrict__ w2, const float* __restrict__ wq,
                  const float* __restrict__ wk, const float* __restrict__ wv,
                  unsigned short* __restrict__ wpk, unsigned short* __restrict__ w1k,
                  unsigned short* __restrict__ w2k, unsigned short* __restrict__ wqk,
                  unsigned short* __restrict__ wkk, unsigned short* __restrict__ wvk,
                  unsigned short* __restrict__ kpb, unsigned short* __restrict__ vtb)
{
  if (blockIdx.x < 128) {
    const int base = blockIdx.x * 1024 + threadIdx.x * 4;
    #pragma unroll
    for (int i = 0; i < 4; ++i) {
      const int tid = base + i;                       // < 131072
      if (tid < 16384) {                              // wp: [128][128]
        const int e = tid & 7, l = (tid >> 3) & 63, j = (tid >> 9) & 7, c = tid >> 12;
        wpk[tid] = f2b(wp[(32*c + 8*(l>>4) + e) * 128 + 16*j + (l & 15)]);
      } else if (tid < 49152) {                       // w1: [128][256]
        const int t2 = tid - 16384;
        const int e = t2 & 7, l = (t2 >> 3) & 63, j = (t2 >> 9) & 15, c = t2 >> 13;
        w1k[t2] = f2b(w1[(32*c + 8*(l>>4) + e) * 256 + 16*j + (l & 15)]);
      } else if (tid < 81920) {                       // w2: [256][128]
        const int t2 = tid - 49152;
        const int e = t2 & 7, l = (t2 >> 3) & 63, j = (t2 >> 9) & 7, c = t2 >> 12;
        w2k[t2] = f2b(w2[(32*c + 8*(l>>4) + e) * 128 + 16*j + (l & 15)]);
      } else {                                        // wq/wk/wv: [128][128]
        const int t2 = (tid - 81920) & 16383;
        const int which = (tid - 81920) >> 14;
        const float* src = which == 0 ? wq : which == 1 ? wk : wv;
        unsigned short* dst = which == 0 ? wqk : which == 1 ? wkk : wvk;
        const int e = t2 & 7, l = (t2 >> 3) & 63, j = (t2 >> 9) & 7, c = t2 >> 12;
        dst[t2] = f2b(src[(32*c + 8*(l>>4) + e) * 128 + 16*j + (l & 15)]);
      }
    }
  } else {
    // zero kpb buffer positions 2496..2559 (proj rewrites real keys 2496..2519 after)
    const int base = (blockIdx.x - 128) * 256 + threadIdx.x;   // 0..511
    for (int i = base; i < 16384; i += 512) {
      const int bm = i >> 11, rem = i & 2047;
      kpb[((size_t)bm * NKP + 2496 + (rem >> 5)) * DH + (rem & 31)] = 0;
      vtb[((size_t)(i >> 6)) * NKP + 2496 + (i & 63)] = 0;
    }
  }
}

// ---------------- Kernel 2: fused MFMA LN+project for K, V and Q ----------------
__global__ __launch_bounds__(256)
void proj_kernel(const float* __restrict__ kin, const float* __restrict__ vin,
                 const float* __restrict__ lnk_g, const float* __restrict__ lnk_b,
                 const unsigned short* __restrict__ wkk, const float* __restrict__ bk,
                 const float* __restrict__ lnv_g, const float* __restrict__ lnv_b,
                 const unsigned short* __restrict__ wvk, const float* __restrict__ bv,
                 unsigned short* __restrict__ kpb, unsigned short* __restrict__ vtb,
                 const float* __restrict__ qin,
                 const float* __restrict__ lnq_g, const float* __restrict__ lnq_b,
                 const unsigned short* __restrict__ wqk, const float* __restrict__ bq,
                 unsigned short* __restrict__ qsb)
{
  const int wid = threadIdx.x >> 6, lane = threadIdx.x & 63;
  const int l15 = lane & 15, g = lane >> 4;

  if (blockIdx.x < 158) {
    const int T = blockIdx.x * 4 + wid;
    if (T >= 630) return;
    const int ph = T >= 315 ? 1 : 0;
    const int t = ph ? T - 315 : T;

    const float* in = ph ? vin : kin;
    const float* gg = ph ? lnv_g : lnk_g;
    const float* bb = ph ? lnv_b : lnk_b;
    const unsigned short* wf = ph ? wvk : wkk;
    const float* bs = ph ? bv : bk;

    const int myrow = 16 * t + l15;
    const int cam = myrow / HK, kk = myrow - cam * HK;

    float x[4][8];
    float s = 0.f, s2 = 0.f;
    #pragma unroll
    for (int c = 0; c < 4; ++c)
      #pragma unroll
      for (int e = 0; e < 8; ++e) {
        const float xv = in[((size_t)(cam * D_ + 32 * c + 8 * g + e)) * HK + kk];
        x[c][e] = xv; s += xv; s2 += xv * xv;
      }
    s  += __shfl_xor(s, 16);  s2 += __shfl_xor(s2, 16);
    s  += __shfl_xor(s, 32);  s2 += __shfl_xor(s2, 32);
    const float mean = s * (1.f / 128.f);
    const float rstd = rsqrtf(s2 * (1.f / 128.f) - mean * mean + 1e-5f);

    short8v aA[4];
    #pragma unroll
    for (int c = 0; c < 4; ++c)
      #pragma unroll
      for (int e = 0; e < 8; ++e) {
        const int col = 32 * c + 8 * g + e;
        aA[c][e] = (short)f2b((x[c][e] - mean) * rstd * gg[col] + bb[col]);
      }

    f32x4 z[8];
    #pragma unroll
    for (int j = 0; j < 8; ++j) {
      f32x4 d = {0.f, 0.f, 0.f, 0.f};
      #pragma unroll
      for (int c = 0; c < 4; ++c) {
        const short8v w8 = *(const short8v*)(wf + (((c * 8 + j) * 64 + lane) << 3));
        d = __builtin_amdgcn_mfma_f32_16x16x32_bf16(aA[c], w8, d, 0, 0, 0);
      }
      z[j] = d;
    }

    const int key0 = 16 * t + 4 * g;
    #pragma unroll
    for (int j = 0; j < 8; ++j) {
      const int col = 16 * j + l15;
      const float bsv = bs[col];
      if (ph == 0) {
        const int m = col >> 5, dh = col & 31;
        #pragma unroll
        for (int r = 0; r < 4; ++r) {
          const int key = key0 + r;
          const int bbx = key / NK, kb = key - bbx * NK;
          const int kbp = (kb & ~31) | kperm(kb & 31);        // permuted chunk position
          kpb[((size_t)(bbx * M_ + m) * NKP + kbp) * DH + dh] = f2b(z[j][r] + bsv);
        }
      } else {
        #pragma unroll
        for (int r = 0; r < 4; ++r) {
          const int key = key0 + r;
          const int bbx = key / NK, kb = key - bbx * NK;
          vtb[((size_t)(bbx * 128 + col)) * NKP + kb] = f2b(z[j][r] + bsv);
        }
      }
    }
  } else {
    const int t = (blockIdx.x - 158) * 4 + wid;
    if (t >= 313) return;
    int myrow = 16 * t + l15; if (myrow > 4999) myrow = 4999;
    const int b = myrow / Q_, qpos = myrow - b * Q_;

    float xs[4][8];
    #pragma unroll
    for (int c = 0; c < 4; ++c)
      #pragma unroll
      for (int e = 0; e < 8; ++e) xs[c][e] = 0.f;

    #pragma unroll
    for (int n = 0; n < 2; ++n) {
      float x[4][8];
      float s = 0.f, s2 = 0.f;
      #pragma unroll
      for (int c = 0; c < 4; ++c)
        #pragma unroll
        for (int e = 0; e < 8; ++e) {
          const float xv = qin[((size_t)((b * N_ + n) * D_ + 32 * c + 8 * g + e)) * Q_ + qpos];
          x[c][e] = xv; s += xv; s2 += xv * xv;
        }
      s  += __shfl_xor(s, 16);  s2 += __shfl_xor(s2, 16);
      s  += __shfl_xor(s, 32);  s2 += __shfl_xor(s2, 32);
      const float mean = s * (1.f / 128.f);
      const float rstd = rsqrtf(s2 * (1.f / 128.f) - mean * mean + 1e-5f);
      #pragma unroll
      for (int c = 0; c < 4; ++c)
        #pragma unroll
        for (int e = 0; e < 8; ++e) xs[c][e] += (x[c][e] - mean) * rstd;
    }

    short8v aA[4];
    #pragma unroll
    for (int c = 0; c < 4; ++c) {
      #pragma unroll
      for (int e = 0; e < 8; ++e) {
        const int col = 32 * c + 8 * g + e;
        aA[c][e] = (short)f2b(SCALE * (xs[c][e] * lnq_g[col] + 2.f * lnq_b[col]));
      }
    }

    f32x4 z[8];
    #pragma unroll
    for (int j = 0; j < 8; ++j) {
      f32x4 d = {0.f, 0.f, 0.f, 0.f};
      #pragma unroll
      for (int c = 0; c < 4; ++c) {
        const short8v w8 = *(const short8v*)(wqk + (((c * 8 + j) * 64 + lane) << 3));
        d = __builtin_amdgcn_mfma_f32_16x16x32_bf16(aA[c], w8, d, 0, 0, 0);
      }
      z[j] = d;
    }

    const int row0 = 16 * t + 4 * g;
    #pragma unroll
    for (int j = 0; j < 8; ++j) {
      const int col = 16 * j + l15;
      const float bsv = 2.f * SCALE * bq[col];
      #pragma unroll
      for (int r = 0; r < 4; ++r) {
        const int row = row0 + r;
        if (row < 5000) qsb[((size_t)row) * 128 + col] = f2b(z[j][r] + bsv);
      }
    }
  }
}

// ---------------- Kernel 3: MFMA flash attention — 2 q-tiles per wave; SPLIT=16 for occupancy ----------------
__global__ __launch_bounds__(256)
void attn_kernel(const unsigned short* __restrict__ qsb,
                 const unsigned short* __restrict__ kpb,
                 const unsigned short* __restrict__ vtb,
                 float* __restrict__ pl, unsigned short* __restrict__ pacc)
{
  const int wid  = threadIdx.x >> 6;
  const int lane = threadIdx.x & 63;
  const int bi = blockIdx.x;
  const int sp = bi & 15;
  const int tmp = bi >> 4;
  const int qg = tmp % 20;
  const int bm = tmp / 20;               // b*4+m
  const int qp = qg * 4 + wid;           // q-tile pair 0..79 -> tiles 2qp, 2qp+1

  const int q16 = lane & 15, g = lane >> 4;
  const int qa = (2 * qp) * 16 + q16;
  const int qb = (2 * qp + 1) * 16 + q16;
  const int qca = qa < Q_ ? qa : Q_ - 1;
  const int qcb = qb < Q_ ? qb : Q_ - 1;
  const int b = bm >> 2;

  const short8v qf0 = *(const short8v*)(qsb + ((size_t)(b * Q_ + qca)) * 128 + (bm & 3) * DH + g * 8);
  const short8v qf1 = *(const short8v*)(qsb + ((size_t)(b * Q_ + qcb)) * 128 + (bm & 3) * DH + g * 8);

  const unsigned short* kbase = kpb + ((size_t)bm * NKP + sp * KPSP) * DH + q16 * DH + g * 8;
  const unsigned short* vbase = vtb + ((size_t)(bm * DH + q16)) * NKP + sp * KPSP + g * 8;

  f32x4 o0a = {0,0,0,0}, o1a = {0,0,0,0}, o0b = {0,0,0,0}, o1b = {0,0,0,0};
  float la = 0.f, lb = 0.f;

  const int c0 = qp % CHUNKS;
  int c1 = c0 + 1; if (c1 >= CHUNKS) c1 -= CHUNKS;
  int cn = c0 + 2; if (cn >= CHUNKS) cn -= CHUNKS;

  short8v kA1 = *(const short8v*)(kbase + c0 * 1024);
  short8v kA2 = *(const short8v*)(kbase + c0 * 1024 + 512);
  short8v vA1 = *(const short8v*)(vbase + c0 * 32);
  short8v vA2 = *(const short8v*)(vbase + c0 * 32 + 16 * NKP);
  short8v kB1 = *(const short8v*)(kbase + c1 * 1024);
  short8v kB2 = *(const short8v*)(kbase + c1 * 1024 + 512);
  short8v vB1 = *(const short8v*)(vbase + c1 * 32);
  short8v vB2 = *(const short8v*)(vbase + c1 * 32 + 16 * NKP);

  auto step = [&](short8v& K1r, short8v& K2r, short8v& V1r, short8v& V2r, int cnx, bool pf) {
    // Permuted K: lane (q16,g) gets S for keys 8g+r (s0*) and 8g+4+r (s1*)
    f32x4 s0a = __builtin_amdgcn_mfma_f32_16x16x32_bf16(K1r, qf0, (f32x4){0.f,0.f,0.f,0.f}, 0, 0, 0);
    f32x4 s1a = __builtin_amdgcn_mfma_f32_16x16x32_bf16(K2r, qf0, (f32x4){0.f,0.f,0.f,0.f}, 0, 0, 0);
    f32x4 s0b = __builtin_amdgcn_mfma_f32_16x16x32_bf16(K1r, qf1, (f32x4){0.f,0.f,0.f,0.f}, 0, 0, 0);
    f32x4 s1b = __builtin_amdgcn_mfma_f32_16x16x32_bf16(K2r, qf1, (f32x4){0.f,0.f,0.f,0.f}, 0, 0, 0);

    if (pf) {
      K1r = *(const short8v*)(kbase + cnx * 1024);
      K2r = *(const short8v*)(kbase + cnx * 1024 + 512);
    }

    float pa[8], pb_[8];
    #pragma unroll
    for (int r = 0; r < 4; ++r) {
      pa[r] = __builtin_amdgcn_exp2f(s0a[r]);  pa[4 + r] = __builtin_amdgcn_exp2f(s1a[r]);
      pb_[r] = __builtin_amdgcn_exp2f(s0b[r]); pb_[4 + r] = __builtin_amdgcn_exp2f(s1b[r]);
    }
    #pragma unroll
    for (int i = 0; i < 8; ++i) { la += pa[i]; lb += pb_[i]; }

    short8v fa, fb;
    #pragma unroll
    for (int i = 0; i < 8; ++i) { fa[i] = (short)f2b(pa[i]); fb[i] = (short)f2b(pb_[i]); }

    o0a = __builtin_amdgcn_mfma_f32_16x16x32_bf16(V1r, fa, o0a, 0, 0, 0);
    o1a = __builtin_amdgcn_mfma_f32_16x16x32_bf16(V2r, fa, o1a, 0, 0, 0);
    o0b = __builtin_amdgcn_mfma_f32_16x16x32_bf16(V1r, fb, o0b, 0, 0, 0);
    o1b = __builtin_amdgcn_mfma_f32_16x16x32_bf16(V2r, fb, o1b, 0, 0, 0);

    if (pf) {
      V1r = *(const short8v*)(vbase + cnx * 32);
      V2r = *(const short8v*)(vbase + cnx * 32 + 16 * NKP);
    }
  };

  // CHUNKS = 5: A,B,A,B,A with prefetch on the first three steps
  step(kA1, kA2, vA1, vA2, cn, true);
  cn = cn + 1 >= CHUNKS ? cn + 1 - CHUNKS : cn + 1;
  step(kB1, kB2, vB1, vB2, cn, true);
  cn = cn + 1 >= CHUNKS ? cn + 1 - CHUNKS : cn + 1;
  step(kA1, kA2, vA1, vA2, cn, true);
  step(kB1, kB2, vB1, vB2, 0, false);
  step(kA1, kA2, vA1, vA2, 0, false);

  la += __shfl_xor(la, 16);  la += __shfl_xor(la, 32);
  lb += __shfl_xor(lb, 16);  lb += __shfl_xor(lb, 32);

  // nontemporal bf16 partials: keep the write stream out of L2 so K/V stay resident
  if (qa < Q_) {
    const size_t row = (size_t)(bm * SPLIT + sp) * Q_ + qa;
    if (lane < 16) __builtin_nontemporal_store(la, &pl[row]);
    u32x2 w0, w1;
    w0[0] = pk2(o0a[0], o0a[1]); w0[1] = pk2(o0a[2], o0a[3]);
    w1[0] = pk2(o1a[0], o1a[1]); w1[1] = pk2(o1a[2], o1a[3]);
    __builtin_nontemporal_store(w0, (u32x2*)(pacc + row * DH + 4 * g));
    __builtin_nontemporal_store(w1, (u32x2*)(pacc + row * DH + 16 + 4 * g));
  }
  if (qb < Q_) {
    const size_t row = (size_t)(bm * SPLIT + sp) * Q_ + qb;
    if (lane < 16) __builtin_nontemporal_store(lb, &pl[row]);
    u32x2 w0, w1;
    w0[0] = pk2(o0b[0], o0b[1]); w0[1] = pk2(o0b[2], o0b[3]);
    w1[0] = pk2(o1b[0], o1b[1]); w1[1] = pk2(o1b[2], o1b[3]);
    __builtin_nontemporal_store(w0, (u32x2*)(pacc + row * DH + 4 * g));
    __builtin_nontemporal_store(w1, (u32x2*)(pacc + row * DH + 16 + 4 * g));
  }
}

// ---------------- Kernel 4: fused combine + MFMA tail, 4 waves cooperate on one 16-row tile ----------------
__global__ __launch_bounds__(256)
void tail_kernel(const float* __restrict__ pl, const unsigned short* __restrict__ pacc,
                 const float* __restrict__ skip,
                 const unsigned short* __restrict__ wpk, const float* __restrict__ bp,
                 const float* __restrict__ ln1_g, const float* __restrict__ ln1_b,
                 const unsigned short* __restrict__ w1k, const float* __restrict__ b1,
                 const unsigned short* __restrict__ w2k, const float* __restrict__ b2,
                 const float* __restrict__ ln2_g, const float* __restrict__ ln2_b,
                 float* __restrict__ out)
{
  __shared__ __align__(16) unsigned short aL[16][136];
  __shared__ __align__(16) unsigned short zl[16][136];
  __shared__ __align__(16) unsigned short hl[16][264];
  __shared__ __align__(16) float stat1[4][16][2];
  __shared__ __align__(16) float stat2[4][16][2];

  const int wid = threadIdx.x >> 6, lane = threadIdx.x & 63;
  const int l15 = lane & 15, g = lane >> 4;
  const int row0 = blockIdx.x * 16;
  const int grow0 = row0 + 4 * g;

  {
    int arow = row0 + l15; if (arow > 4999) arow = 4999;
    const int bb = arow / Q_, qq = arow - bb * Q_;
    float ls = -40.0f;                   // exact correction for 40 zero-pad keys
    float4 a0 = {0,0,0,0}, a1 = {0,0,0,0};
    #pragma unroll
    for (int sp = 0; sp < SPLIT; ++sp) {
      const size_t row = (size_t)((bb * 4 + wid) * SPLIT + sp) * Q_ + qq;
      ls += __builtin_nontemporal_load(&pl[row]);
      const u32x4 t = __builtin_nontemporal_load((const u32x4*)(pacc + row * DH + 8 * g));
      a0.x += bl(t[0]); a0.y += bh(t[0]); a0.z += bl(t[1]); a0.w += bh(t[1]);
      a1.x += bl(t[2]); a1.y += bh(t[2]); a1.z += bl(t[3]); a1.w += bh(t[3]);
    }
    const float inv = 1.f / ls;
    u32x4 w;
    w[0] = pk2(a0.x * inv, a0.y * inv);
    w[1] = pk2(a0.z * inv, a0.w * inv);
    w[2] = pk2(a1.x * inv, a1.y * inv);
    w[3] = pk2(a1.z * inv, a1.w * inv);
    *(u32x4*)&aL[l15][32 * wid + 8 * g] = w;
  }
  __syncthreads();

  short8v aA[4];
  #pragma unroll
  for (int c = 0; c < 4; ++c)
    aA[c] = *(const short8v*)&aL[l15][32 * c + 8 * g];

  f32x4 zres[2];
  #pragma unroll
  for (int jj = 0; jj < 2; ++jj) {
    const int j = 2 * wid + jj;
    f32x4 d = {0.f, 0.f, 0.f, 0.f};
    #pragma unroll
    for (int c = 0; c < 4; ++c) {
      const short8v wf = *(const short8v*)(wpk + (((c * 8 + j) * 64 + lane) << 3));
      d = __builtin_amdgcn_mfma_f32_16x16x32_bf16(aA[c], wf, d, 0, 0, 0);
    }
    zres[jj] = d;
  }

  #pragma unroll
  for (int jj = 0; jj < 2; ++jj) {
    const int col = 16 * (2 * wid + jj) + l15;
    const float bpv = bp[col];
    #pragma unroll
    for (int r = 0; r < 4; ++r) {
      int rr = grow0 + r; if (rr > 4999) rr = 4999;
      const int bb = rr / 2500, q = rr - bb * 2500;
      zres[jj][r] += bpv + skip[((size_t)(bb * 128 + col)) * 2500 + q];
    }
  }

  {
    float sum[4], sq[4];
    #pragma unroll
    for (int r = 0; r < 4; ++r) {
      sum[r] = zres[0][r] + zres[1][r];
      sq[r]  = zres[0][r] * zres[0][r] + zres[1][r] * zres[1][r];
    }
    #pragma unroll
    for (int r = 0; r < 4; ++r) {
      #pragma unroll
      for (int off = 1; off < 16; off <<= 1) {
        sum[r] += __shfl_xor(sum[r], off);
        sq[r]  += __shfl_xor(sq[r], off);
      }
    }
    if (l15 == 0) {
      float4 s0 = {sum[0], sq[0], sum[1], sq[1]};
      float4 s1 = {sum[2], sq[2], sum[3], sq[3]};
      *(float4*)&stat1[wid][4 * g][0]     = s0;
      *(float4*)&stat1[wid][4 * g + 2][0] = s1;
    }
  }
  __syncthreads();

  float mean[4], rstd[4];
  #pragma unroll
  for (int r = 0; r < 4; ++r) {
    float S = 0.f, S2 = 0.f;
    #pragma unroll
    for (int w2 = 0; w2 < 4; ++w2) {
      S  += stat1[w2][4 * g + r][0];
      S2 += stat1[w2][4 * g + r][1];
    }
    mean[r] = S * (1.f / 128.f);
    rstd[r] = rsqrtf(S2 * (1.f / 128.f) - mean[r] * mean[r] + 1e-5f);
  }

  #pragma unroll
  for (int jj = 0; jj < 2; ++jj) {
    const int col = 16 * (2 * wid + jj) + l15;
    const float g1 = ln1_g[col], bv1 = ln1_b[col];
    #pragma unroll
    for (int r = 0; r < 4; ++r) {
      const float vv = (zres[jj][r] - mean[r]) * rstd[r] * g1 + bv1;
      zres[jj][r] = vv;
      zl[4 * g + r][col] = f2b(vv);
    }
  }
  __syncthreads();

  short8v zA[4];
  #pragma unroll
  for (int c = 0; c < 4; ++c)
    zA[c] = *(const short8v*)&zl[l15][32 * c + 8 * g];
  #pragma unroll
  for (int jj = 0; jj < 4; ++jj) {
    const int j = 4 * wid + jj;
    f32x4 d = {0.f, 0.f, 0.f, 0.f};
    #pragma unroll
    for (int c = 0; c < 4; ++c) {
      const short8v wf = *(const short8v*)(w1k + (((c * 16 + j) * 64 + lane) << 3));
      d = __builtin_amdgcn_mfma_f32_16x16x32_bf16(zA[c], wf, d, 0, 0, 0);
    }
    const int col = 16 * j + l15;
    const float bv = b1[col];
    #pragma unroll
    for (int r = 0; r < 4; ++r) {
      const float x = d[r] + bv;
      hl[4 * g + r][col] = f2b(0.5f * x * (1.f + erff(x * 0.70710678118654752f)));
    }
  }
  __syncthreads();

  short8v hA[8];
  #pragma unroll
  for (int c = 0; c < 8; ++c)
    hA[c] = *(const short8v*)&hl[l15][32 * c + 8 * g];
  #pragma unroll
  for (int jj = 0; jj < 2; ++jj) {
    const int j = 2 * wid + jj;
    f32x4 d = {0.f, 0.f, 0.f, 0.f};
    #pragma unroll
    for (int c = 0; c < 8; ++c) {
      const short8v wf = *(const short8v*)(w2k + (((c * 8 + j) * 64 + lane) << 3));
      d = __builtin_amdgcn_mfma_f32_16x16x32_bf16(hA[c], wf, d, 0, 0, 0);
    }
    const int col = 16 * j + l15;
    const float bv = b2[col];
    #pragma unroll
    for (int r = 0; r < 4; ++r) zres[jj][r] += d[r] + bv;
  }

  {
    float sum[4], sq[4];
    #pragma unroll
    for (int r = 0; r < 4; ++r) {
      sum[r] = zres[0][r] + zres[1][r];
      sq[r]  = zres[0][r] * zres[0][r] + zres[1][r] * zres[1][r];
    }
    #pragma unroll
    for (int r = 0; r < 4; ++r) {
      #pragma unroll
      for (int off = 1; off < 16; off <<= 1) {
        sum[r] += __shfl_xor(sum[r], off);
        sq[r]  += __shfl_xor(sq[r], off);
      }
    }
    if (l15 == 0) {
      float4 s0 = {sum[0], sq[0], sum[1], sq[1]};
      float4 s1 = {sum[2], sq[2], sum[3], sq[3]};
      *(float4*)&stat2[wid][4 * g][0]     = s0;
      *(float4*)&stat2[wid][4 * g + 2][0] = s1;
    }
  }
  __syncthreads();

  float mean2[4], rstd2[4];
  #pragma unroll
  for (int r = 0; r < 4; ++r) {
    float S = 0.f, S2 = 0.f;
    #pragma unroll
    for (int w2 = 0; w2 < 4; ++w2) {
      S  += stat2[w2][4 * g + r][0];
      S2 += stat2[w2][4 * g + r][1];
    }
    mean2[r] = S * (1.f / 128.f);
    rstd2[r] = rsqrtf(S2 * (1.f / 128.f) - mean2[r] * mean2[r] + 1e-5f);
  }

  if (grow0 + 3 <= 4999) {
    const int bb = grow0 / 2500, q0 = grow0 - bb * 2500;
    #pragma unroll
    for (int jj = 0; jj < 2; ++jj) {
      const int col = 16 * (2 * wid + jj) + l15;
      const float g2 = ln2_g[col], bv2 = ln2_b[col];
      float4 o;
      o.x = (zres[jj][0] - mean2[0]) * rstd2[0] * g2 + bv2;
      o.y = (zres[jj][1] - mean2[1]) * rstd2[1] * g2 + bv2;
      o.z = (zres[jj][2] - mean2[2]) * rstd2[2] * g2 + bv2;
      o.w = (zres[jj][3] - mean2[3]) * rstd2[3] * g2 + bv2;
      *(float4*)(out + ((size_t)(bb * 128 + col)) * 2500 + q0) = o;
    }
  }
}

extern "C" void kernel_launch(void* const* d_in, const int* in_sizes, int n_in,
                              void* d_out, int out_size, void* d_ws, size_t ws_size,
                              hipStream_t stream)
{
  const float* q     = (const float*)d_in[0];
  const float* k     = (const float*)d_in[1];
  const float* v     = (const float*)d_in[2];
  const float* skip  = (const float*)d_in[3];
  const float* lnq_g = (const float*)d_in[4];
  const float* lnq_b = (const float*)d_in[5];
  const float* wq    = (const float*)d_in[6];
  const float* bq    = (const float*)d_in[7];
  const float* lnk_g = (const float*)d_in[8];
  const float* lnk_b = (const float*)d_in[9];
  const float* wk    = (const float*)d_in[10];
  const float* bk    = (const float*)d_in[11];
  const float* lnv_g = (const float*)d_in[12];
  const float* lnv_b = (const float*)d_in[13];
  const float* wv    = (const float*)d_in[14];
  const float* bv    = (const float*)d_in[15];
  const float* wp    = (const float*)d_in[16];
  const float* bp    = (const float*)d_in[17];
  const float* ln1_g = (const float*)d_in[18];
  const float* ln1_b = (const float*)d_in[19];
  const float* w1    = (const float*)d_in[20];
  const float* b1    = (const float*)d_in[21];
  const float* w2    = (const float*)d_in[22];
  const float* b2    = (const float*)d_in[23];
  const float* ln2_g = (const float*)d_in[24];
  const float* ln2_b = (const float*)d_in[25];

  unsigned short* kpb = (unsigned short*)d_ws;         // 655360
  unsigned short* vtb = kpb + 655360;                  // 655360
  unsigned short* qsb = vtb + 655360;                  // 640000
  unsigned short* wpk = qsb + 640000;                  // 16384
  unsigned short* w1k = wpk + 16384;                   // 32768
  unsigned short* w2k = w1k + 32768;                   // 32768
  unsigned short* wqk = w2k + 32768;                   // 16384
  unsigned short* wkk = wqk + 16384;                   // 16384
  unsigned short* wvk = wkk + 16384;                   // 16384
  float* pl = (float*)(wvk + 16384);                   // 2*4*16*2500 = 320000 floats
  unsigned short* pacc = (unsigned short*)(pl + 320000); // 320000*32 bf16 shorts

  setup_kernel<<<dim3(130), dim3(256), 0, stream>>>(wp, w1, w2, wq, wk, wv,
                                                    wpk, w1k, w2k, wqk, wkk, wvk,
                                                    kpb, vtb);
  proj_kernel<<<dim3(237), dim3(256), 0, stream>>>(
      k, v, lnk_g, lnk_b, wkk, bk, lnv_g, lnv_b, wvk, bv, kpb, vtb,
      q, lnq_g, lnq_b, wqk, bq, qsb);
  attn_kernel<<<dim3(2560), dim3(256), 0, stream>>>(qsb, kpb, vtb, pl, pacc);
  tail_kernel<<<dim3(313), dim3(256), 0, stream>>>(
      pl, pacc, skip, wpk, bp, ln1_g, ln1_b, w1k, b1, w2k, b2, ln2_g, ln2_b, (float*)d_out);
}

// Round 14
// 58.937 us; speedup vs baseline: 1.0758x; 1.0758x over previous
//
#include <hip/hip_runtime.h>
#include <hip/hip_bf16.h>
#include <math.h>

#define B_  2
#define N_  6
#define D_  128
#define Q_  2500
#define HK  420
#define NK  2520
#define NKP 2560      // padded keys (40 zero-pads)
#define M_  4
#define DH  32
#define SPLIT 8
#define KPSP 320      // NKP/SPLIT
#define CHUNKS 10     // KPSP/32
#define SCALE 0.25503487775f   // 32^-0.5 * log2(e); attn uses exp2

typedef __attribute__((ext_vector_type(8))) short short8v;
typedef __attribute__((ext_vector_type(4))) float f32x4;
typedef __attribute__((ext_vector_type(2))) unsigned u32x2;
typedef __attribute__((ext_vector_type(4))) unsigned u32x4;

__device__ __forceinline__ unsigned short f2b(float x) {
  unsigned u = __float_as_uint(x);
  return (unsigned short)((u + 0x7FFFu + ((u >> 16) & 1u)) >> 16);
}

__device__ __forceinline__ unsigned pk2(float lo, float hi) {
  return (unsigned)f2b(lo) | ((unsigned)f2b(hi) << 16);
}

__device__ __forceinline__ float bl(unsigned u) { return __uint_as_float(u << 16); }
__device__ __forceinline__ float bh(unsigned u) { return __uint_as_float(u & 0xffff0000u); }

// K-chunk storage permutation: actual key a (0..31) -> buffer position p so that
// the QK^T D-layout lands P[8g+e] directly in lane (q16,g)'s PV B-frag slots.
__device__ __forceinline__ int kperm(int a) {
  const int h = a & 7;
  return ((h >= 4) ? 16 : 0) + 4 * (a >> 3) + (h & 3);
}

// ---------------- Kernel 1: prepack weights to MFMA B-frag order + zero pad chunks ----------------
__global__ __launch_bounds__(256)
void setup_kernel(const float* __restrict__ wp, const float* __restrict__ w1,
                  const float* __restrict__ w2, const float* __restrict__ wq,
                  const float* __restrict__ wk, const float* __restrict__ wv,
                  unsigned short* __restrict__ wpk, unsigned short* __restrict__ w1k,
                  unsigned short* __restrict__ w2k, unsigned short* __restrict__ wqk,
                  unsigned short* __restrict__ wkk, unsigned short* __restrict__ wvk,
                  unsigned short* __restrict__ kpb, unsigned short* __restrict__ vtb)
{
  if (blockIdx.x < 128) {
    const int base = blockIdx.x * 1024 + threadIdx.x * 4;
    #pragma unroll
    for (int i = 0; i < 4; ++i) {
      const int tid = base + i;                       // < 131072
      if (tid < 16384) {                              // wp: [128][128]
        const int e = tid & 7, l = (tid >> 3) & 63, j = (tid >> 9) & 7, c = tid >> 12;
        wpk[tid] = f2b(wp[(32*c + 8*(l>>4) + e) * 128 + 16*j + (l & 15)]);
      } else if (tid < 49152) {                       // w1: [128][256]
        const int t2 = tid - 16384;
        const int e = t2 & 7, l = (t2 >> 3) & 63, j = (t2 >> 9) & 15, c = t2 >> 13;
        w1k[t2] = f2b(w1[(32*c + 8*(l>>4) + e) * 256 + 16*j + (l & 15)]);
      } else if (tid < 81920) {                       // w2: [256][128]
        const int t2 = tid - 49152;
        const int e = t2 & 7, l = (t2 >> 3) & 63, j = (t2 >> 9) & 7, c = t2 >> 12;
        w2k[t2] = f2b(w2[(32*c + 8*(l>>4) + e) * 128 + 16*j + (l & 15)]);
      } else {                                        // wq/wk/wv: [128][128]
        const int t2 = (tid - 81920) & 16383;
        const int which = (tid - 81920) >> 14;
        const float* src = which == 0 ? wq : which == 1 ? wk : wv;
        unsigned short* dst = which == 0 ? wqk : which == 1 ? wkk : wvk;
        const int e = t2 & 7, l = (t2 >> 3) & 63, j = (t2 >> 9) & 7, c = t2 >> 12;
        dst[t2] = f2b(src[(32*c + 8*(l>>4) + e) * 128 + 16*j + (l & 15)]);
      }
    }
  } else {
    // zero kpb buffer positions 2496..2559 (proj rewrites real keys 2496..2519 after)
    const int base = (blockIdx.x - 128) * 256 + threadIdx.x;   // 0..511
    for (int i = base; i < 16384; i += 512) {
      const int bm = i >> 11, rem = i & 2047;
      kpb[((size_t)bm * NKP + 2496 + (rem >> 5)) * DH + (rem & 31)] = 0;
      vtb[((size_t)(i >> 6)) * NKP + 2496 + (i & 63)] = 0;
    }
  }
}

// ---------------- Kernel 2: fused MFMA LN+project for K, V and Q ----------------
__global__ __launch_bounds__(256)
void proj_kernel(const float* __restrict__ kin, const float* __restrict__ vin,
                 const float* __restrict__ lnk_g, const float* __restrict__ lnk_b,
                 const unsigned short* __restrict__ wkk, const float* __restrict__ bk,
                 const float* __restrict__ lnv_g, const float* __restrict__ lnv_b,
                 const unsigned short* __restrict__ wvk, const float* __restrict__ bv,
                 unsigned short* __restrict__ kpb, unsigned short* __restrict__ vtb,
                 const float* __restrict__ qin,
                 const float* __restrict__ lnq_g, const float* __restrict__ lnq_b,
                 const unsigned short* __restrict__ wqk, const float* __restrict__ bq,
                 unsigned short* __restrict__ qsb)
{
  const int wid = threadIdx.x >> 6, lane = threadIdx.x & 63;
  const int l15 = lane & 15, g = lane >> 4;

  if (blockIdx.x < 158) {
    const int T = blockIdx.x * 4 + wid;
    if (T >= 630) return;
    const int ph = T >= 315 ? 1 : 0;
    const int t = ph ? T - 315 : T;

    const float* in = ph ? vin : kin;
    const float* gg = ph ? lnv_g : lnk_g;
    const float* bb = ph ? lnv_b : lnk_b;
    const unsigned short* wf = ph ? wvk : wkk;
    const float* bs = ph ? bv : bk;

    const int myrow = 16 * t + l15;
    const int cam = myrow / HK, kk = myrow - cam * HK;

    float x[4][8];
    float s = 0.f, s2 = 0.f;
    #pragma unroll
    for (int c = 0; c < 4; ++c)
      #pragma unroll
      for (int e = 0; e < 8; ++e) {
        const float xv = in[((size_t)(cam * D_ + 32 * c + 8 * g + e)) * HK + kk];
        x[c][e] = xv; s += xv; s2 += xv * xv;
      }
    s  += __shfl_xor(s, 16);  s2 += __shfl_xor(s2, 16);
    s  += __shfl_xor(s, 32);  s2 += __shfl_xor(s2, 32);
    const float mean = s * (1.f / 128.f);
    const float rstd = rsqrtf(s2 * (1.f / 128.f) - mean * mean + 1e-5f);

    short8v aA[4];
    #pragma unroll
    for (int c = 0; c < 4; ++c)
      #pragma unroll
      for (int e = 0; e < 8; ++e) {
        const int col = 32 * c + 8 * g + e;
        aA[c][e] = (short)f2b((x[c][e] - mean) * rstd * gg[col] + bb[col]);
      }

    f32x4 z[8];
    #pragma unroll
    for (int j = 0; j < 8; ++j) {
      f32x4 d = {0.f, 0.f, 0.f, 0.f};
      #pragma unroll
      for (int c = 0; c < 4; ++c) {
        const short8v w8 = *(const short8v*)(wf + (((c * 8 + j) * 64 + lane) << 3));
        d = __builtin_amdgcn_mfma_f32_16x16x32_bf16(aA[c], w8, d, 0, 0, 0);
      }
      z[j] = d;
    }

    const int key0 = 16 * t + 4 * g;
    #pragma unroll
    for (int j = 0; j < 8; ++j) {
      const int col = 16 * j + l15;
      const float bsv = bs[col];
      if (ph == 0) {
        const int m = col >> 5, dh = col & 31;
        #pragma unroll
        for (int r = 0; r < 4; ++r) {
          const int key = key0 + r;
          const int bbx = key / NK, kb = key - bbx * NK;
          const int kbp = (kb & ~31) | kperm(kb & 31);        // permuted chunk position
          kpb[((size_t)(bbx * M_ + m) * NKP + kbp) * DH + dh] = f2b(z[j][r] + bsv);
        }
      } else {
        #pragma unroll
        for (int r = 0; r < 4; ++r) {
          const int key = key0 + r;
          const int bbx = key / NK, kb = key - bbx * NK;
          vtb[((size_t)(bbx * 128 + col)) * NKP + kb] = f2b(z[j][r] + bsv);
        }
      }
    }
  } else {
    const int t = (blockIdx.x - 158) * 4 + wid;
    if (t >= 313) return;
    int myrow = 16 * t + l15; if (myrow > 4999) myrow = 4999;
    const int b = myrow / Q_, qpos = myrow - b * Q_;

    float xs[4][8];
    #pragma unroll
    for (int c = 0; c < 4; ++c)
      #pragma unroll
      for (int e = 0; e < 8; ++e) xs[c][e] = 0.f;

    #pragma unroll
    for (int n = 0; n < 2; ++n) {
      float x[4][8];
      float s = 0.f, s2 = 0.f;
      #pragma unroll
      for (int c = 0; c < 4; ++c)
        #pragma unroll
        for (int e = 0; e < 8; ++e) {
          const float xv = qin[((size_t)((b * N_ + n) * D_ + 32 * c + 8 * g + e)) * Q_ + qpos];
          x[c][e] = xv; s += xv; s2 += xv * xv;
        }
      s  += __shfl_xor(s, 16);  s2 += __shfl_xor(s2, 16);
      s  += __shfl_xor(s, 32);  s2 += __shfl_xor(s2, 32);
      const float mean = s * (1.f / 128.f);
      const float rstd = rsqrtf(s2 * (1.f / 128.f) - mean * mean + 1e-5f);
      #pragma unroll
      for (int c = 0; c < 4; ++c)
        #pragma unroll
        for (int e = 0; e < 8; ++e) xs[c][e] += (x[c][e] - mean) * rstd;
    }

    short8v aA[4];
    #pragma unroll
    for (int c = 0; c < 4; ++c) {
      #pragma unroll
      for (int e = 0; e < 8; ++e) {
        const int col = 32 * c + 8 * g + e;
        aA[c][e] = (short)f2b(SCALE * (xs[c][e] * lnq_g[col] + 2.f * lnq_b[col]));
      }
    }

    f32x4 z[8];
    #pragma unroll
    for (int j = 0; j < 8; ++j) {
      f32x4 d = {0.f, 0.f, 0.f, 0.f};
      #pragma unroll
      for (int c = 0; c < 4; ++c) {
        const short8v w8 = *(const short8v*)(wqk + (((c * 8 + j) * 64 + lane) << 3));
        d = __builtin_amdgcn_mfma_f32_16x16x32_bf16(aA[c], w8, d, 0, 0, 0);
      }
      z[j] = d;
    }

    const int row0 = 16 * t + 4 * g;
    #pragma unroll
    for (int j = 0; j < 8; ++j) {
      const int col = 16 * j + l15;
      const float bsv = 2.f * SCALE * bq[col];
      #pragma unroll
      for (int r = 0; r < 4; ++r) {
        const int row = row0 + r;
        if (row < 5000) qsb[((size_t)row) * 128 + col] = f2b(z[j][r] + bsv);
      }
    }
  }
}

// ---------------- Kernel 3: MFMA flash attention — 4 q-tiles per wave share K/V stream ----------------
__global__ __launch_bounds__(256)
void attn_kernel(const unsigned short* __restrict__ qsb,
                 const unsigned short* __restrict__ kpb,
                 const unsigned short* __restrict__ vtb,
                 float* __restrict__ pl, unsigned short* __restrict__ pacc)
{
  const int wid  = threadIdx.x >> 6;
  const int lane = threadIdx.x & 63;
  const int bi = blockIdx.x;
  const int sp = bi & 7;
  const int tmp = bi >> 3;
  const int qqg = tmp % 10;
  const int bm = tmp / 10;               // b*4+m
  const int quad = qqg * 4 + wid;        // 0..39 -> tiles 4quad..4quad+3

  const int q16 = lane & 15, g = lane >> 4;
  const int b = bm >> 2;

  int qx[4];
  short8v qf0, qf1, qf2, qf3;
  {
    #pragma unroll
    for (int i = 0; i < 4; ++i) qx[i] = (4 * quad + i) * 16 + q16;
    const int c0i = qx[0] < Q_ ? qx[0] : Q_ - 1;
    const int c1i = qx[1] < Q_ ? qx[1] : Q_ - 1;
    const int c2i = qx[2] < Q_ ? qx[2] : Q_ - 1;
    const int c3i = qx[3] < Q_ ? qx[3] : Q_ - 1;
    const size_t off = (bm & 3) * DH + g * 8;
    qf0 = *(const short8v*)(qsb + ((size_t)(b * Q_ + c0i)) * 128 + off);
    qf1 = *(const short8v*)(qsb + ((size_t)(b * Q_ + c1i)) * 128 + off);
    qf2 = *(const short8v*)(qsb + ((size_t)(b * Q_ + c2i)) * 128 + off);
    qf3 = *(const short8v*)(qsb + ((size_t)(b * Q_ + c3i)) * 128 + off);
  }

  const unsigned short* kbase = kpb + ((size_t)bm * NKP + sp * KPSP) * DH + q16 * DH + g * 8;
  const unsigned short* vbase = vtb + ((size_t)(bm * DH + q16)) * NKP + sp * KPSP + g * 8;

  f32x4 o0_0 = {0,0,0,0}, o1_0 = {0,0,0,0};
  f32x4 o0_1 = {0,0,0,0}, o1_1 = {0,0,0,0};
  f32x4 o0_2 = {0,0,0,0}, o1_2 = {0,0,0,0};
  f32x4 o0_3 = {0,0,0,0}, o1_3 = {0,0,0,0};
  float l0 = 0.f, l1 = 0.f, l2 = 0.f, l3 = 0.f;

  const int c0 = quad % CHUNKS;
  int c1 = c0 + 1; if (c1 >= CHUNKS) c1 -= CHUNKS;
  int cn = c0 + 2; if (cn >= CHUNKS) cn -= CHUNKS;

  short8v kA1 = *(const short8v*)(kbase + c0 * 1024);
  short8v kA2 = *(const short8v*)(kbase + c0 * 1024 + 512);
  short8v vA1 = *(const short8v*)(vbase + c0 * 32);
  short8v vA2 = *(const short8v*)(vbase + c0 * 32 + 16 * NKP);
  short8v kB1 = *(const short8v*)(kbase + c1 * 1024);
  short8v kB2 = *(const short8v*)(kbase + c1 * 1024 + 512);
  short8v vB1 = *(const short8v*)(vbase + c1 * 32);
  short8v vB2 = *(const short8v*)(vbase + c1 * 32 + 16 * NKP);

  auto step = [&](short8v& K1r, short8v& K2r, short8v& V1r, short8v& V2r, int cnx) {
    // Permuted K: lane (q16,g) gets S for keys 8g+r (s0) and 8g+4+r (s1), per q-tile
    f32x4 s0_0 = __builtin_amdgcn_mfma_f32_16x16x32_bf16(K1r, qf0, (f32x4){0.f,0.f,0.f,0.f}, 0, 0, 0);
    f32x4 s1_0 = __builtin_amdgcn_mfma_f32_16x16x32_bf16(K2r, qf0, (f32x4){0.f,0.f,0.f,0.f}, 0, 0, 0);
    f32x4 s0_1 = __builtin_amdgcn_mfma_f32_16x16x32_bf16(K1r, qf1, (f32x4){0.f,0.f,0.f,0.f}, 0, 0, 0);
    f32x4 s1_1 = __builtin_amdgcn_mfma_f32_16x16x32_bf16(K2r, qf1, (f32x4){0.f,0.f,0.f,0.f}, 0, 0, 0);
    f32x4 s0_2 = __builtin_amdgcn_mfma_f32_16x16x32_bf16(K1r, qf2, (f32x4){0.f,0.f,0.f,0.f}, 0, 0, 0);
    f32x4 s1_2 = __builtin_amdgcn_mfma_f32_16x16x32_bf16(K2r, qf2, (f32x4){0.f,0.f,0.f,0.f}, 0, 0, 0);
    f32x4 s0_3 = __builtin_amdgcn_mfma_f32_16x16x32_bf16(K1r, qf3, (f32x4){0.f,0.f,0.f,0.f}, 0, 0, 0);
    f32x4 s1_3 = __builtin_amdgcn_mfma_f32_16x16x32_bf16(K2r, qf3, (f32x4){0.f,0.f,0.f,0.f}, 0, 0, 0);

    K1r = *(const short8v*)(kbase + cnx * 1024);
    K2r = *(const short8v*)(kbase + cnx * 1024 + 512);

    u32x4 u0, u1, u2, u3;
    float p0, p1;
    #pragma unroll
    for (int j = 0; j < 4; ++j) {
      const int r0 = 2 * j, r1 = 2 * j + 1;
      const float a0 = __builtin_amdgcn_exp2f(j < 2 ? s0_0[r0] : s1_0[r0 - 4]);
      const float a1 = __builtin_amdgcn_exp2f(j < 2 ? s0_0[r1] : s1_0[r1 - 4]);
      l0 += a0 + a1; u0[j] = pk2(a0, a1);
      const float b0 = __builtin_amdgcn_exp2f(j < 2 ? s0_1[r0] : s1_1[r0 - 4]);
      const float b1 = __builtin_amdgcn_exp2f(j < 2 ? s0_1[r1] : s1_1[r1 - 4]);
      l1 += b0 + b1; u1[j] = pk2(b0, b1);
      const float cc0 = __builtin_amdgcn_exp2f(j < 2 ? s0_2[r0] : s1_2[r0 - 4]);
      const float cc1 = __builtin_amdgcn_exp2f(j < 2 ? s0_2[r1] : s1_2[r1 - 4]);
      l2 += cc0 + cc1; u2[j] = pk2(cc0, cc1);
      const float d0 = __builtin_amdgcn_exp2f(j < 2 ? s0_3[r0] : s1_3[r0 - 4]);
      const float d1 = __builtin_amdgcn_exp2f(j < 2 ? s0_3[r1] : s1_3[r1 - 4]);
      l3 += d0 + d1; u3[j] = pk2(d0, d1);
    }
    const short8v f0 = __builtin_bit_cast(short8v, u0);
    const short8v f1 = __builtin_bit_cast(short8v, u1);
    const short8v f2 = __builtin_bit_cast(short8v, u2);
    const short8v f3 = __builtin_bit_cast(short8v, u3);

    o0_0 = __builtin_amdgcn_mfma_f32_16x16x32_bf16(V1r, f0, o0_0, 0, 0, 0);
    o1_0 = __builtin_amdgcn_mfma_f32_16x16x32_bf16(V2r, f0, o1_0, 0, 0, 0);
    o0_1 = __builtin_amdgcn_mfma_f32_16x16x32_bf16(V1r, f1, o0_1, 0, 0, 0);
    o1_1 = __builtin_amdgcn_mfma_f32_16x16x32_bf16(V2r, f1, o1_1, 0, 0, 0);
    o0_2 = __builtin_amdgcn_mfma_f32_16x16x32_bf16(V1r, f2, o0_2, 0, 0, 0);
    o1_2 = __builtin_amdgcn_mfma_f32_16x16x32_bf16(V2r, f2, o1_2, 0, 0, 0);
    o0_3 = __builtin_amdgcn_mfma_f32_16x16x32_bf16(V1r, f3, o0_3, 0, 0, 0);
    o1_3 = __builtin_amdgcn_mfma_f32_16x16x32_bf16(V2r, f3, o1_3, 0, 0, 0);

    V1r = *(const short8v*)(vbase + cnx * 32);
    V2r = *(const short8v*)(vbase + cnx * 32 + 16 * NKP);
  };

  #pragma unroll 1
  for (int it = 0; it < CHUNKS / 2; ++it) {
    step(kA1, kA2, vA1, vA2, cn);
    cn = cn + 1 >= CHUNKS ? cn + 1 - CHUNKS : cn + 1;
    step(kB1, kB2, vB1, vB2, cn);
    cn = cn + 1 >= CHUNKS ? cn + 1 - CHUNKS : cn + 1;
  }

  l0 += __shfl_xor(l0, 16);  l0 += __shfl_xor(l0, 32);
  l1 += __shfl_xor(l1, 16);  l1 += __shfl_xor(l1, 32);
  l2 += __shfl_xor(l2, 16);  l2 += __shfl_xor(l2, 32);
  l3 += __shfl_xor(l3, 16);  l3 += __shfl_xor(l3, 32);

  const size_t rbase = (size_t)(bm * SPLIT + sp) * Q_;
  #pragma unroll
  for (int i = 0; i < 4; ++i) {
    const f32x4 oo0 = i == 0 ? o0_0 : i == 1 ? o0_1 : i == 2 ? o0_2 : o0_3;
    const f32x4 oo1 = i == 0 ? o1_0 : i == 1 ? o1_1 : i == 2 ? o1_2 : o1_3;
    const float ll  = i == 0 ? l0 : i == 1 ? l1 : i == 2 ? l2 : l3;
    if (qx[i] < Q_) {
      const size_t row = rbase + qx[i];
      if (lane < 16) __builtin_nontemporal_store(ll, &pl[row]);
      u32x2 w0, w1;
      w0[0] = pk2(oo0[0], oo0[1]); w0[1] = pk2(oo0[2], oo0[3]);
      w1[0] = pk2(oo1[0], oo1[1]); w1[1] = pk2(oo1[2], oo1[3]);
      __builtin_nontemporal_store(w0, (u32x2*)(pacc + row * DH + 4 * g));
      __builtin_nontemporal_store(w1, (u32x2*)(pacc + row * DH + 16 + 4 * g));
    }
  }
}

// ---------------- Kernel 4: fused combine + MFMA tail, 4 waves cooperate on one 16-row tile ----------------
__global__ __launch_bounds__(256)
void tail_kernel(const float* __restrict__ pl, const unsigned short* __restrict__ pacc,
                 const float* __restrict__ skip,
                 const unsigned short* __restrict__ wpk, const float* __restrict__ bp,
                 const float* __restrict__ ln1_g, const float* __restrict__ ln1_b,
                 const unsigned short* __restrict__ w1k, const float* __restrict__ b1,
                 const unsigned short* __restrict__ w2k, const float* __restrict__ b2,
                 const float* __restrict__ ln2_g, const float* __restrict__ ln2_b,
                 float* __restrict__ out)
{
  __shared__ __align__(16) unsigned short aL[16][136];
  __shared__ __align__(16) unsigned short zl[16][136];
  __shared__ __align__(16) unsigned short hl[16][264];
  __shared__ __align__(16) float stat1[4][16][2];
  __shared__ __align__(16) float stat2[4][16][2];

  const int wid = threadIdx.x >> 6, lane = threadIdx.x & 63;
  const int l15 = lane & 15, g = lane >> 4;
  const int row0 = blockIdx.x * 16;
  const int grow0 = row0 + 4 * g;

  {
    int arow = row0 + l15; if (arow > 4999) arow = 4999;
    const int bb = arow / Q_, qq = arow - bb * Q_;
    float ls = -40.0f;                   // exact correction for 40 zero-pad keys
    float4 a0 = {0,0,0,0}, a1 = {0,0,0,0};
    #pragma unroll
    for (int sp = 0; sp < SPLIT; ++sp) {
      const size_t row = (size_t)((bb * 4 + wid) * SPLIT + sp) * Q_ + qq;
      ls += __builtin_nontemporal_load(&pl[row]);
      const u32x4 t = __builtin_nontemporal_load((const u32x4*)(pacc + row * DH + 8 * g));
      a0.x += bl(t[0]); a0.y += bh(t[0]); a0.z += bl(t[1]); a0.w += bh(t[1]);
      a1.x += bl(t[2]); a1.y += bh(t[2]); a1.z += bl(t[3]); a1.w += bh(t[3]);
    }
    const float inv = 1.f / ls;
    u32x4 w;
    w[0] = pk2(a0.x * inv, a0.y * inv);
    w[1] = pk2(a0.z * inv, a0.w * inv);
    w[2] = pk2(a1.x * inv, a1.y * inv);
    w[3] = pk2(a1.z * inv, a1.w * inv);
    *(u32x4*)&aL[l15][32 * wid + 8 * g] = w;
  }
  __syncthreads();

  short8v aA[4];
  #pragma unroll
  for (int c = 0; c < 4; ++c)
    aA[c] = *(const short8v*)&aL[l15][32 * c + 8 * g];

  f32x4 zres[2];
  #pragma unroll
  for (int jj = 0; jj < 2; ++jj) {
    const int j = 2 * wid + jj;
    f32x4 d = {0.f, 0.f, 0.f, 0.f};
    #pragma unroll
    for (int c = 0; c < 4; ++c) {
      const short8v wf = *(const short8v*)(wpk + (((c * 8 + j) * 64 + lane) << 3));
      d = __builtin_amdgcn_mfma_f32_16x16x32_bf16(aA[c], wf, d, 0, 0, 0);
    }
    zres[jj] = d;
  }

  #pragma unroll
  for (int jj = 0; jj < 2; ++jj) {
    const int col = 16 * (2 * wid + jj) + l15;
    const float bpv = bp[col];
    #pragma unroll
    for (int r = 0; r < 4; ++r) {
      int rr = grow0 + r; if (rr > 4999) rr = 4999;
      const int bb = rr / 2500, q = rr - bb * 2500;
      zres[jj][r] += bpv + skip[((size_t)(bb * 128 + col)) * 2500 + q];
    }
  }

  {
    float sum[4], sq[4];
    #pragma unroll
    for (int r = 0; r < 4; ++r) {
      sum[r] = zres[0][r] + zres[1][r];
      sq[r]  = zres[0][r] * zres[0][r] + zres[1][r] * zres[1][r];
    }
    #pragma unroll
    for (int r = 0; r < 4; ++r) {
      #pragma unroll
      for (int off = 1; off < 16; off <<= 1) {
        sum[r] += __shfl_xor(sum[r], off);
        sq[r]  += __shfl_xor(sq[r], off);
      }
    }
    if (l15 == 0) {
      float4 s0 = {sum[0], sq[0], sum[1], sq[1]};
      float4 s1 = {sum[2], sq[2], sum[3], sq[3]};
      *(float4*)&stat1[wid][4 * g][0]     = s0;
      *(float4*)&stat1[wid][4 * g + 2][0] = s1;
    }
  }
  __syncthreads();

  float mean[4], rstd[4];
  #pragma unroll
  for (int r = 0; r < 4; ++r) {
    float S = 0.f, S2 = 0.f;
    #pragma unroll
    for (int w2 = 0; w2 < 4; ++w2) {
      S  += stat1[w2][4 * g + r][0];
      S2 += stat1[w2][4 * g + r][1];
    }
    mean[r] = S * (1.f / 128.f);
    rstd[r] = rsqrtf(S2 * (1.f / 128.f) - mean[r] * mean[r] + 1e-5f);
  }

  #pragma unroll
  for (int jj = 0; jj < 2; ++jj) {
    const int col = 16 * (2 * wid + jj) + l15;
    const float g1 = ln1_g[col], bv1 = ln1_b[col];
    #pragma unroll
    for (int r = 0; r < 4; ++r) {
      const float vv = (zres[jj][r] - mean[r]) * rstd[r] * g1 + bv1;
      zres[jj][r] = vv;
      zl[4 * g + r][col] = f2b(vv);
    }
  }
  __syncthreads();

  short8v zA[4];
  #pragma unroll
  for (int c = 0; c < 4; ++c)
    zA[c] = *(const short8v*)&zl[l15][32 * c + 8 * g];
  #pragma unroll
  for (int jj = 0; jj < 4; ++jj) {
    const int j = 4 * wid + jj;
    f32x4 d = {0.f, 0.f, 0.f, 0.f};
    #pragma unroll
    for (int c = 0; c < 4; ++c) {
      const short8v wf = *(const short8v*)(w1k + (((c * 16 + j) * 64 + lane) << 3));
      d = __builtin_amdgcn_mfma_f32_16x16x32_bf16(zA[c], wf, d, 0, 0, 0);
    }
    const int col = 16 * j + l15;
    const float bv = b1[col];
    #pragma unroll
    for (int r = 0; r < 4; ++r) {
      const float x = d[r] + bv;
      hl[4 * g + r][col] = f2b(0.5f * x * (1.f + erff(x * 0.70710678118654752f)));
    }
  }
  __syncthreads();

  short8v hA[8];
  #pragma unroll
  for (int c = 0; c < 8; ++c)
    hA[c] = *(const short8v*)&hl[l15][32 * c + 8 * g];
  #pragma unroll
  for (int jj = 0; jj < 2; ++jj) {
    const int j = 2 * wid + jj;
    f32x4 d = {0.f, 0.f, 0.f, 0.f};
    #pragma unroll
    for (int c = 0; c < 8; ++c) {
      const short8v wf = *(const short8v*)(w2k + (((c * 8 + j) * 64 + lane) << 3));
      d = __builtin_amdgcn_mfma_f32_16x16x32_bf16(hA[c], wf, d, 0, 0, 0);
    }
    const int col = 16 * j + l15;
    const float bv = b2[col];
    #pragma unroll
    for (int r = 0; r < 4; ++r) zres[jj][r] += d[r] + bv;
  }

  {
    float sum[4], sq[4];
    #pragma unroll
    for (int r = 0; r < 4; ++r) {
      sum[r] = zres[0][r] + zres[1][r];
      sq[r]  = zres[0][r] * zres[0][r] + zres[1][r] * zres[1][r];
    }
    #pragma unroll
    for (int r = 0; r < 4; ++r) {
      #pragma unroll
      for (int off = 1; off < 16; off <<= 1) {
        sum[r] += __shfl_xor(sum[r], off);
        sq[r]  += __shfl_xor(sq[r], off);
      }
    }
    if (l15 == 0) {
      float4 s0 = {sum[0], sq[0], sum[1], sq[1]};
      float4 s1 = {sum[2], sq[2], sum[3], sq[3]};
      *(float4*)&stat2[wid][4 * g][0]     = s0;
      *(float4*)&stat2[wid][4 * g + 2][0] = s1;
    }
  }
  __syncthreads();

  float mean2[4], rstd2[4];
  #pragma unroll
  for (int r = 0; r < 4; ++r) {
    float S = 0.f, S2 = 0.f;
    #pragma unroll
    for (int w2 = 0; w2 < 4; ++w2) {
      S  += stat2[w2][4 * g + r][0];
      S2 += stat2[w2][4 * g + r][1];
    }
    mean2[r] = S * (1.f / 128.f);
    rstd2[r] = rsqrtf(S2 * (1.f / 128.f) - mean2[r] * mean2[r] + 1e-5f);
  }

  if (grow0 + 3 <= 4999) {
    const int bb = grow0 / 2500, q0 = grow0 - bb * 2500;
    #pragma unroll
    for (int jj = 0; jj < 2; ++jj) {
      const int col = 16 * (2 * wid + jj) + l15;
      const float g2 = ln2_g[col], bv2 = ln2_b[col];
      float4 o;
      o.x = (zres[jj][0] - mean2[0]) * rstd2[0] * g2 + bv2;
      o.y = (zres[jj][1] - mean2[1]) * rstd2[1] * g2 + bv2;
      o.z = (zres[jj][2] - mean2[2]) * rstd2[2] * g2 + bv2;
      o.w = (zres[jj][3] - mean2[3]) * rstd2[3] * g2 + bv2;
      *(float4*)(out + ((size_t)(bb * 128 + col)) * 2500 + q0) = o;
    }
  }
}

extern "C" void kernel_launch(void* const* d_in, const int* in_sizes, int n_in,
                              void* d_out, int out_size, void* d_ws, size_t ws_size,
                              hipStream_t stream)
{
  const float* q     = (const float*)d_in[0];
  const float* k     = (const float*)d_in[1];
  const float* v     = (const float*)d_in[2];
  const float* skip  = (const float*)d_in[3];
  const float* lnq_g = (const float*)d_in[4];
  const float* lnq_b = (const float*)d_in[5];
  const float* wq    = (const float*)d_in[6];
  const float* bq    = (const float*)d_in[7];
  const float* lnk_g = (const float*)d_in[8];
  const float* lnk_b = (const float*)d_in[9];
  const float* wk    = (const float*)d_in[10];
  const float* bk    = (const float*)d_in[11];
  const float* lnv_g = (const float*)d_in[12];
  const float* lnv_b = (const float*)d_in[13];
  const float* wv    = (const float*)d_in[14];
  const float* bv    = (const float*)d_in[15];
  const float* wp    = (const float*)d_in[16];
  const float* bp    = (const float*)d_in[17];
  const float* ln1_g = (const float*)d_in[18];
  const float* ln1_b = (const float*)d_in[19];
  const float* w1    = (const float*)d_in[20];
  const float* b1    = (const float*)d_in[21];
  const float* w2    = (const float*)d_in[22];
  const float* b2    = (const float*)d_in[23];
  const float* ln2_g = (const float*)d_in[24];
  const float* ln2_b = (const float*)d_in[25];

  unsigned short* kpb = (unsigned short*)d_ws;         // 655360
  unsigned short* vtb = kpb + 655360;                  // 655360
  unsigned short* qsb = vtb + 655360;                  // 640000
  unsigned short* wpk = qsb + 640000;                  // 16384
  unsigned short* w1k = wpk + 16384;                   // 32768
  unsigned short* w2k = w1k + 32768;                   // 32768
  unsigned short* wqk = w2k + 32768;                   // 16384
  unsigned short* wkk = wqk + 16384;                   // 16384
  unsigned short* wvk = wkk + 16384;                   // 16384
  float* pl = (float*)(wvk + 16384);                   // 2*4*8*2500 = 160000 floats
  unsigned short* pacc = (unsigned short*)(pl + 160000); // 160000*32 bf16 shorts

  setup_kernel<<<dim3(130), dim3(256), 0, stream>>>(wp, w1, w2, wq, wk, wv,
                                                    wpk, w1k, w2k, wqk, wkk, wvk,
                                                    kpb, vtb);
  proj_kernel<<<dim3(237), dim3(256), 0, stream>>>(
      k, v, lnk_g, lnk_b, wkk, bk, lnv_g, lnv_b, wvk, bv, kpb, vtb,
      q, lnq_g, lnq_b, wqk, bq, qsb);
  attn_kernel<<<dim3(640), dim3(256), 0, stream>>>(qsb, kpb, vtb, pl, pacc);
  tail_kernel<<<dim3(313), dim3(256), 0, stream>>>(
      pl, pacc, skip, wpk, bp, ln1_g, ln1_b, w1k, b1, w2k, b2, ln2_g, ln2_b, (float*)d_out);
}

// Round 15
// 53.799 us; speedup vs baseline: 1.1785x; 1.0955x over previous
//
#include <hip/hip_runtime.h>
#include <hip/hip_bf16.h>
#include <math.h>

#define B_  2
#define N_  6
#define D_  128
#define Q_  2500
#define HK  420
#define NK  2520
#define NKP 2560      // padded keys (40 zero-pads)
#define M_  4
#define DH  32
#define SPLIT 8
#define KPSP 320      // NKP/SPLIT
#define CHUNKS 10     // KPSP/32
#define SCALE 0.25503487775f   // 32^-0.5 * log2(e); attn uses exp2

typedef __attribute__((ext_vector_type(8))) short short8v;
typedef __attribute__((ext_vector_type(4))) float f32x4;
typedef __attribute__((ext_vector_type(2))) unsigned u32x2;
typedef __attribute__((ext_vector_type(4))) unsigned u32x4;

__device__ __forceinline__ unsigned short f2b(float x) {
  unsigned u = __float_as_uint(x);
  return (unsigned short)((u + 0x7FFFu + ((u >> 16) & 1u)) >> 16);
}

// HW packed f32->bf16 (RNE), replaces ~12 VALU ops with 1
__device__ __forceinline__ unsigned cvtpk(float lo, float hi) {
  unsigned r;
  asm("v_cvt_pk_bf16_f32 %0, %1, %2" : "=v"(r) : "v"(lo), "v"(hi));
  return r;
}

__device__ __forceinline__ float bl(unsigned u) { return __uint_as_float(u << 16); }
__device__ __forceinline__ float bh(unsigned u) { return __uint_as_float(u & 0xffff0000u); }

// K-chunk storage permutation: actual key a (0..31) -> buffer position p so that
// the QK^T D-layout lands P[8g+e] directly in lane (q16,g)'s PV B-frag slots.
__device__ __forceinline__ int kperm(int a) {
  const int h = a & 7;
  return ((h >= 4) ? 16 : 0) + 4 * (a >> 3) + (h & 3);
}

// ---------------- Kernel 1: prepack weights to MFMA B-frag order + zero pad chunks ----------------
__global__ __launch_bounds__(256)
void setup_kernel(const float* __restrict__ wp, const float* __restrict__ w1,
                  const float* __restrict__ w2, const float* __restrict__ wq,
                  const float* __restrict__ wk, const float* __restrict__ wv,
                  unsigned short* __restrict__ wpk, unsigned short* __restrict__ w1k,
                  unsigned short* __restrict__ w2k, unsigned short* __restrict__ wqk,
                  unsigned short* __restrict__ wkk, unsigned short* __restrict__ wvk,
                  unsigned short* __restrict__ kpb, unsigned short* __restrict__ vtb)
{
  if (blockIdx.x < 128) {
    const int base = blockIdx.x * 1024 + threadIdx.x * 4;
    #pragma unroll
    for (int i = 0; i < 4; ++i) {
      const int tid = base + i;                       // < 131072
      if (tid < 16384) {                              // wp: [128][128]
        const int e = tid & 7, l = (tid >> 3) & 63, j = (tid >> 9) & 7, c = tid >> 12;
        wpk[tid] = f2b(wp[(32*c + 8*(l>>4) + e) * 128 + 16*j + (l & 15)]);
      } else if (tid < 49152) {                       // w1: [128][256]
        const int t2 = tid - 16384;
        const int e = t2 & 7, l = (t2 >> 3) & 63, j = (t2 >> 9) & 15, c = t2 >> 13;
        w1k[t2] = f2b(w1[(32*c + 8*(l>>4) + e) * 256 + 16*j + (l & 15)]);
      } else if (tid < 81920) {                       // w2: [256][128]
        const int t2 = tid - 49152;
        const int e = t2 & 7, l = (t2 >> 3) & 63, j = (t2 >> 9) & 7, c = t2 >> 12;
        w2k[t2] = f2b(w2[(32*c + 8*(l>>4) + e) * 128 + 16*j + (l & 15)]);
      } else {                                        // wq/wk/wv: [128][128]
        const int t2 = (tid - 81920) & 16383;
        const int which = (tid - 81920) >> 14;
        const float* src = which == 0 ? wq : which == 1 ? wk : wv;
        unsigned short* dst = which == 0 ? wqk : which == 1 ? wkk : wvk;
        const int e = t2 & 7, l = (t2 >> 3) & 63, j = (t2 >> 9) & 7, c = t2 >> 12;
        dst[t2] = f2b(src[(32*c + 8*(l>>4) + e) * 128 + 16*j + (l & 15)]);
      }
    }
  } else {
    // zero kpb buffer positions 2496..2559 (proj rewrites real keys 2496..2519 after)
    const int base = (blockIdx.x - 128) * 256 + threadIdx.x;   // 0..511
    for (int i = base; i < 16384; i += 512) {
      const int bm = i >> 11, rem = i & 2047;
      kpb[((size_t)bm * NKP + 2496 + (rem >> 5)) * DH + (rem & 31)] = 0;
      vtb[((size_t)(i >> 6)) * NKP + 2496 + (i & 63)] = 0;
    }
  }
}

// ---------------- Kernel 2: fused MFMA LN+project for K, V and Q ----------------
__global__ __launch_bounds__(256)
void proj_kernel(const float* __restrict__ kin, const float* __restrict__ vin,
                 const float* __restrict__ lnk_g, const float* __restrict__ lnk_b,
                 const unsigned short* __restrict__ wkk, const float* __restrict__ bk,
                 const float* __restrict__ lnv_g, const float* __restrict__ lnv_b,
                 const unsigned short* __restrict__ wvk, const float* __restrict__ bv,
                 unsigned short* __restrict__ kpb, unsigned short* __restrict__ vtb,
                 const float* __restrict__ qin,
                 const float* __restrict__ lnq_g, const float* __restrict__ lnq_b,
                 const unsigned short* __restrict__ wqk, const float* __restrict__ bq,
                 unsigned short* __restrict__ qsb)
{
  const int wid = threadIdx.x >> 6, lane = threadIdx.x & 63;
  const int l15 = lane & 15, g = lane >> 4;

  if (blockIdx.x < 158) {
    const int T = blockIdx.x * 4 + wid;
    if (T >= 630) return;
    const int ph = T >= 315 ? 1 : 0;
    const int t = ph ? T - 315 : T;

    const float* in = ph ? vin : kin;
    const float* gg = ph ? lnv_g : lnk_g;
    const float* bb = ph ? lnv_b : lnk_b;
    const unsigned short* wf = ph ? wvk : wkk;
    const float* bs = ph ? bv : bk;

    const int myrow = 16 * t + l15;
    const int cam = myrow / HK, kk = myrow - cam * HK;

    float x[4][8];
    float s = 0.f, s2 = 0.f;
    #pragma unroll
    for (int c = 0; c < 4; ++c)
      #pragma unroll
      for (int e = 0; e < 8; ++e) {
        const float xv = in[((size_t)(cam * D_ + 32 * c + 8 * g + e)) * HK + kk];
        x[c][e] = xv; s += xv; s2 += xv * xv;
      }
    s  += __shfl_xor(s, 16);  s2 += __shfl_xor(s2, 16);
    s  += __shfl_xor(s, 32);  s2 += __shfl_xor(s2, 32);
    const float mean = s * (1.f / 128.f);
    const float rstd = rsqrtf(s2 * (1.f / 128.f) - mean * mean + 1e-5f);

    short8v aA[4];
    #pragma unroll
    for (int c = 0; c < 4; ++c) {
      float xn[8];
      #pragma unroll
      for (int e = 0; e < 8; ++e) {
        const int col = 32 * c + 8 * g + e;
        xn[e] = (x[c][e] - mean) * rstd * gg[col] + bb[col];
      }
      u32x4 u;
      u[0] = cvtpk(xn[0], xn[1]); u[1] = cvtpk(xn[2], xn[3]);
      u[2] = cvtpk(xn[4], xn[5]); u[3] = cvtpk(xn[6], xn[7]);
      aA[c] = __builtin_bit_cast(short8v, u);
    }

    f32x4 z[8];
    #pragma unroll
    for (int j = 0; j < 8; ++j) {
      f32x4 d = {0.f, 0.f, 0.f, 0.f};
      #pragma unroll
      for (int c = 0; c < 4; ++c) {
        const short8v w8 = *(const short8v*)(wf + (((c * 8 + j) * 64 + lane) << 3));
        d = __builtin_amdgcn_mfma_f32_16x16x32_bf16(aA[c], w8, d, 0, 0, 0);
      }
      z[j] = d;
    }

    const int key0 = 16 * t + 4 * g;
    #pragma unroll
    for (int j = 0; j < 8; ++j) {
      const int col = 16 * j + l15;
      const float bsv = bs[col];
      if (ph == 0) {
        const int m = col >> 5, dh = col & 31;
        #pragma unroll
        for (int r = 0; r < 4; ++r) {
          const int key = key0 + r;
          const int bbx = key / NK, kb = key - bbx * NK;
          const int kbp = (kb & ~31) | kperm(kb & 31);        // permuted chunk position
          kpb[((size_t)(bbx * M_ + m) * NKP + kbp) * DH + dh] = f2b(z[j][r] + bsv);
        }
      } else {
        // 4 consecutive keys -> one 8B packed store (key0 is 4-aligned, never straddles b)
        const int bbx = key0 / NK, kb0 = key0 - bbx * NK;
        u32x2 w;
        w[0] = cvtpk(z[j][0] + bsv, z[j][1] + bsv);
        w[1] = cvtpk(z[j][2] + bsv, z[j][3] + bsv);
        *(u32x2*)&vtb[((size_t)(bbx * 128 + col)) * NKP + kb0] = w;
      }
    }
  } else {
    const int t = (blockIdx.x - 158) * 4 + wid;
    if (t >= 313) return;
    int myrow = 16 * t + l15; if (myrow > 4999) myrow = 4999;
    const int b = myrow / Q_, qpos = myrow - b * Q_;

    float xs[4][8];
    #pragma unroll
    for (int c = 0; c < 4; ++c)
      #pragma unroll
      for (int e = 0; e < 8; ++e) xs[c][e] = 0.f;

    #pragma unroll
    for (int n = 0; n < 2; ++n) {
      float x[4][8];
      float s = 0.f, s2 = 0.f;
      #pragma unroll
      for (int c = 0; c < 4; ++c)
        #pragma unroll
        for (int e = 0; e < 8; ++e) {
          const float xv = qin[((size_t)((b * N_ + n) * D_ + 32 * c + 8 * g + e)) * Q_ + qpos];
          x[c][e] = xv; s += xv; s2 += xv * xv;
        }
      s  += __shfl_xor(s, 16);  s2 += __shfl_xor(s2, 16);
      s  += __shfl_xor(s, 32);  s2 += __shfl_xor(s2, 32);
      const float mean = s * (1.f / 128.f);
      const float rstd = rsqrtf(s2 * (1.f / 128.f) - mean * mean + 1e-5f);
      #pragma unroll
      for (int c = 0; c < 4; ++c)
        #pragma unroll
        for (int e = 0; e < 8; ++e) xs[c][e] += (x[c][e] - mean) * rstd;
    }

    short8v aA[4];
    #pragma unroll
    for (int c = 0; c < 4; ++c) {
      float xn[8];
      #pragma unroll
      for (int e = 0; e < 8; ++e) {
        const int col = 32 * c + 8 * g + e;
        xn[e] = SCALE * (xs[c][e] * lnq_g[col] + 2.f * lnq_b[col]);
      }
      u32x4 u;
      u[0] = cvtpk(xn[0], xn[1]); u[1] = cvtpk(xn[2], xn[3]);
      u[2] = cvtpk(xn[4], xn[5]); u[3] = cvtpk(xn[6], xn[7]);
      aA[c] = __builtin_bit_cast(short8v, u);
    }

    f32x4 z[8];
    #pragma unroll
    for (int j = 0; j < 8; ++j) {
      f32x4 d = {0.f, 0.f, 0.f, 0.f};
      #pragma unroll
      for (int c = 0; c < 4; ++c) {
        const short8v w8 = *(const short8v*)(wqk + (((c * 8 + j) * 64 + lane) << 3));
        d = __builtin_amdgcn_mfma_f32_16x16x32_bf16(aA[c], w8, d, 0, 0, 0);
      }
      z[j] = d;
    }

    const int row0 = 16 * t + 4 * g;
    #pragma unroll
    for (int j = 0; j < 8; ++j) {
      const int col = 16 * j + l15;
      const float bsv = 2.f * SCALE * bq[col];
      #pragma unroll
      for (int r = 0; r < 4; ++r) {
        const int row = row0 + r;
        if (row < 5000) qsb[((size_t)row) * 128 + col] = f2b(z[j][r] + bsv);
      }
    }
  }
}

// ---------------- Kernel 3: MFMA flash attention — 4 q-tiles per wave, cvt_pk softmax ----------------
__global__ __launch_bounds__(256)
void attn_kernel(const unsigned short* __restrict__ qsb,
                 const unsigned short* __restrict__ kpb,
                 const unsigned short* __restrict__ vtb,
                 float* __restrict__ pl, unsigned short* __restrict__ pacc)
{
  const int wid  = threadIdx.x >> 6;
  const int lane = threadIdx.x & 63;
  const int bi = blockIdx.x;
  const int sp = bi & 7;
  const int tmp = bi >> 3;
  const int qqg = tmp % 10;
  const int bm = tmp / 10;               // b*4+m
  const int quad = qqg * 4 + wid;        // 0..39 -> tiles 4quad..4quad+3

  const int q16 = lane & 15, g = lane >> 4;
  const int b = bm >> 2;

  int qx[4];
  short8v qf0, qf1, qf2, qf3;
  {
    #pragma unroll
    for (int i = 0; i < 4; ++i) qx[i] = (4 * quad + i) * 16 + q16;
    const int c0i = qx[0] < Q_ ? qx[0] : Q_ - 1;
    const int c1i = qx[1] < Q_ ? qx[1] : Q_ - 1;
    const int c2i = qx[2] < Q_ ? qx[2] : Q_ - 1;
    const int c3i = qx[3] < Q_ ? qx[3] : Q_ - 1;
    const size_t off = (bm & 3) * DH + g * 8;
    qf0 = *(const short8v*)(qsb + ((size_t)(b * Q_ + c0i)) * 128 + off);
    qf1 = *(const short8v*)(qsb + ((size_t)(b * Q_ + c1i)) * 128 + off);
    qf2 = *(const short8v*)(qsb + ((size_t)(b * Q_ + c2i)) * 128 + off);
    qf3 = *(const short8v*)(qsb + ((size_t)(b * Q_ + c3i)) * 128 + off);
  }

  const unsigned short* kbase = kpb + ((size_t)bm * NKP + sp * KPSP) * DH + q16 * DH + g * 8;
  const unsigned short* vbase = vtb + ((size_t)(bm * DH + q16)) * NKP + sp * KPSP + g * 8;

  f32x4 o0_0 = {0,0,0,0}, o1_0 = {0,0,0,0};
  f32x4 o0_1 = {0,0,0,0}, o1_1 = {0,0,0,0};
  f32x4 o0_2 = {0,0,0,0}, o1_2 = {0,0,0,0};
  f32x4 o0_3 = {0,0,0,0}, o1_3 = {0,0,0,0};
  float l0 = 0.f, l1 = 0.f, l2 = 0.f, l3 = 0.f;

  const int c0 = quad % CHUNKS;
  int c1 = c0 + 1; if (c1 >= CHUNKS) c1 -= CHUNKS;
  int cn = c0 + 2; if (cn >= CHUNKS) cn -= CHUNKS;

  short8v kA1 = *(const short8v*)(kbase + c0 * 1024);
  short8v kA2 = *(const short8v*)(kbase + c0 * 1024 + 512);
  short8v vA1 = *(const short8v*)(vbase + c0 * 32);
  short8v vA2 = *(const short8v*)(vbase + c0 * 32 + 16 * NKP);
  short8v kB1 = *(const short8v*)(kbase + c1 * 1024);
  short8v kB2 = *(const short8v*)(kbase + c1 * 1024 + 512);
  short8v vB1 = *(const short8v*)(vbase + c1 * 32);
  short8v vB2 = *(const short8v*)(vbase + c1 * 32 + 16 * NKP);

  auto step = [&](short8v& K1r, short8v& K2r, short8v& V1r, short8v& V2r, int cnx) {
    // Permuted K: lane (q16,g) gets S for keys 8g+r (s0) and 8g+4+r (s1), per q-tile
    f32x4 s0_0 = __builtin_amdgcn_mfma_f32_16x16x32_bf16(K1r, qf0, (f32x4){0.f,0.f,0.f,0.f}, 0, 0, 0);
    f32x4 s1_0 = __builtin_amdgcn_mfma_f32_16x16x32_bf16(K2r, qf0, (f32x4){0.f,0.f,0.f,0.f}, 0, 0, 0);
    f32x4 s0_1 = __builtin_amdgcn_mfma_f32_16x16x32_bf16(K1r, qf1, (f32x4){0.f,0.f,0.f,0.f}, 0, 0, 0);
    f32x4 s1_1 = __builtin_amdgcn_mfma_f32_16x16x32_bf16(K2r, qf1, (f32x4){0.f,0.f,0.f,0.f}, 0, 0, 0);
    f32x4 s0_2 = __builtin_amdgcn_mfma_f32_16x16x32_bf16(K1r, qf2, (f32x4){0.f,0.f,0.f,0.f}, 0, 0, 0);
    f32x4 s1_2 = __builtin_amdgcn_mfma_f32_16x16x32_bf16(K2r, qf2, (f32x4){0.f,0.f,0.f,0.f}, 0, 0, 0);
    f32x4 s0_3 = __builtin_amdgcn_mfma_f32_16x16x32_bf16(K1r, qf3, (f32x4){0.f,0.f,0.f,0.f}, 0, 0, 0);
    f32x4 s1_3 = __builtin_amdgcn_mfma_f32_16x16x32_bf16(K2r, qf3, (f32x4){0.f,0.f,0.f,0.f}, 0, 0, 0);

    K1r = *(const short8v*)(kbase + cnx * 1024);
    K2r = *(const short8v*)(kbase + cnx * 1024 + 512);

    u32x4 u0, u1, u2, u3;
    #pragma unroll
    for (int j = 0; j < 4; ++j) {
      const int r0 = 2 * j, r1 = 2 * j + 1;
      const float a0 = __builtin_amdgcn_exp2f(j < 2 ? s0_0[r0] : s1_0[r0 - 4]);
      const float a1 = __builtin_amdgcn_exp2f(j < 2 ? s0_0[r1] : s1_0[r1 - 4]);
      l0 += a0 + a1; u0[j] = cvtpk(a0, a1);
      const float b0 = __builtin_amdgcn_exp2f(j < 2 ? s0_1[r0] : s1_1[r0 - 4]);
      const float b1 = __builtin_amdgcn_exp2f(j < 2 ? s0_1[r1] : s1_1[r1 - 4]);
      l1 += b0 + b1; u1[j] = cvtpk(b0, b1);
      const float cc0 = __builtin_amdgcn_exp2f(j < 2 ? s0_2[r0] : s1_2[r0 - 4]);
      const float cc1 = __builtin_amdgcn_exp2f(j < 2 ? s0_2[r1] : s1_2[r1 - 4]);
      l2 += cc0 + cc1; u2[j] = cvtpk(cc0, cc1);
      const float d0 = __builtin_amdgcn_exp2f(j < 2 ? s0_3[r0] : s1_3[r0 - 4]);
      const float d1 = __builtin_amdgcn_exp2f(j < 2 ? s0_3[r1] : s1_3[r1 - 4]);
      l3 += d0 + d1; u3[j] = cvtpk(d0, d1);
    }
    const short8v f0 = __builtin_bit_cast(short8v, u0);
    const short8v f1 = __builtin_bit_cast(short8v, u1);
    const short8v f2 = __builtin_bit_cast(short8v, u2);
    const short8v f3 = __builtin_bit_cast(short8v, u3);

    o0_0 = __builtin_amdgcn_mfma_f32_16x16x32_bf16(V1r, f0, o0_0, 0, 0, 0);
    o1_0 = __builtin_amdgcn_mfma_f32_16x16x32_bf16(V2r, f0, o1_0, 0, 0, 0);
    o0_1 = __builtin_amdgcn_mfma_f32_16x16x32_bf16(V1r, f1, o0_1, 0, 0, 0);
    o1_1 = __builtin_amdgcn_mfma_f32_16x16x32_bf16(V2r, f1, o1_1, 0, 0, 0);
    o0_2 = __builtin_amdgcn_mfma_f32_16x16x32_bf16(V1r, f2, o0_2, 0, 0, 0);
    o1_2 = __builtin_amdgcn_mfma_f32_16x16x32_bf16(V2r, f2, o1_2, 0, 0, 0);
    o0_3 = __builtin_amdgcn_mfma_f32_16x16x32_bf16(V1r, f3, o0_3, 0, 0, 0);
    o1_3 = __builtin_amdgcn_mfma_f32_16x16x32_bf16(V2r, f3, o1_3, 0, 0, 0);

    V1r = *(const short8v*)(vbase + cnx * 32);
    V2r = *(const short8v*)(vbase + cnx * 32 + 16 * NKP);
  };

  #pragma unroll 1
  for (int it = 0; it < CHUNKS / 2; ++it) {
    step(kA1, kA2, vA1, vA2, cn);
    cn = cn + 1 >= CHUNKS ? cn + 1 - CHUNKS : cn + 1;
    step(kB1, kB2, vB1, vB2, cn);
    cn = cn + 1 >= CHUNKS ? cn + 1 - CHUNKS : cn + 1;
  }

  l0 += __shfl_xor(l0, 16);  l0 += __shfl_xor(l0, 32);
  l1 += __shfl_xor(l1, 16);  l1 += __shfl_xor(l1, 32);
  l2 += __shfl_xor(l2, 16);  l2 += __shfl_xor(l2, 32);
  l3 += __shfl_xor(l3, 16);  l3 += __shfl_xor(l3, 32);

  const size_t rbase = (size_t)(bm * SPLIT + sp) * Q_;
  #pragma unroll
  for (int i = 0; i < 4; ++i) {
    const f32x4 oo0 = i == 0 ? o0_0 : i == 1 ? o0_1 : i == 2 ? o0_2 : o0_3;
    const f32x4 oo1 = i == 0 ? o1_0 : i == 1 ? o1_1 : i == 2 ? o1_2 : o1_3;
    const float ll  = i == 0 ? l0 : i == 1 ? l1 : i == 2 ? l2 : l3;
    if (qx[i] < Q_) {
      const size_t row = rbase + qx[i];
      if (lane < 16) __builtin_nontemporal_store(ll, &pl[row]);
      u32x2 w0, w1;
      w0[0] = cvtpk(oo0[0], oo0[1]); w0[1] = cvtpk(oo0[2], oo0[3]);
      w1[0] = cvtpk(oo1[0], oo1[1]); w1[1] = cvtpk(oo1[2], oo1[3]);
      __builtin_nontemporal_store(w0, (u32x2*)(pacc + row * DH + 4 * g));
      __builtin_nontemporal_store(w1, (u32x2*)(pacc + row * DH + 16 + 4 * g));
    }
  }
}

// ---------------- Kernel 4: fused combine + MFMA tail, 4 waves cooperate on one 16-row tile ----------------
__global__ __launch_bounds__(256)
void tail_kernel(const float* __restrict__ pl, const unsigned short* __restrict__ pacc,
                 const float* __restrict__ skip,
                 const unsigned short* __restrict__ wpk, const float* __restrict__ bp,
                 const float* __restrict__ ln1_g, const float* __restrict__ ln1_b,
                 const unsigned short* __restrict__ w1k, const float* __restrict__ b1,
                 const unsigned short* __restrict__ w2k, const float* __restrict__ b2,
                 const float* __restrict__ ln2_g, const float* __restrict__ ln2_b,
                 float* __restrict__ out)
{
  __shared__ __align__(16) unsigned short aL[16][136];
  __shared__ __align__(16) unsigned short zl[16][136];
  __shared__ __align__(16) unsigned short hl[16][264];
  __shared__ __align__(16) float stat1[4][16][2];
  __shared__ __align__(16) float stat2[4][16][2];

  const int wid = threadIdx.x >> 6, lane = threadIdx.x & 63;
  const int l15 = lane & 15, g = lane >> 4;
  const int row0 = blockIdx.x * 16;
  const int grow0 = row0 + 4 * g;

  {
    int arow = row0 + l15; if (arow > 4999) arow = 4999;
    const int bb = arow / Q_, qq = arow - bb * Q_;
    float ls = -40.0f;                   // exact correction for 40 zero-pad keys
    float4 a0 = {0,0,0,0}, a1 = {0,0,0,0};
    #pragma unroll
    for (int sp = 0; sp < SPLIT; ++sp) {
      const size_t row = (size_t)((bb * 4 + wid) * SPLIT + sp) * Q_ + qq;
      ls += __builtin_nontemporal_load(&pl[row]);
      const u32x4 t = __builtin_nontemporal_load((const u32x4*)(pacc + row * DH + 8 * g));
      a0.x += bl(t[0]); a0.y += bh(t[0]); a0.z += bl(t[1]); a0.w += bh(t[1]);
      a1.x += bl(t[2]); a1.y += bh(t[2]); a1.z += bl(t[3]); a1.w += bh(t[3]);
    }
    const float inv = 1.f / ls;
    u32x4 w;
    w[0] = cvtpk(a0.x * inv, a0.y * inv);
    w[1] = cvtpk(a0.z * inv, a0.w * inv);
    w[2] = cvtpk(a1.x * inv, a1.y * inv);
    w[3] = cvtpk(a1.z * inv, a1.w * inv);
    *(u32x4*)&aL[l15][32 * wid + 8 * g] = w;
  }
  __syncthreads();

  short8v aA[4];
  #pragma unroll
  for (int c = 0; c < 4; ++c)
    aA[c] = *(const short8v*)&aL[l15][32 * c + 8 * g];

  f32x4 zres[2];
  #pragma unroll
  for (int jj = 0; jj < 2; ++jj) {
    const int j = 2 * wid + jj;
    f32x4 d = {0.f, 0.f, 0.f, 0.f};
    #pragma unroll
    for (int c = 0; c < 4; ++c) {
      const short8v wf = *(const short8v*)(wpk + (((c * 8 + j) * 64 + lane) << 3));
      d = __builtin_amdgcn_mfma_f32_16x16x32_bf16(aA[c], wf, d, 0, 0, 0);
    }
    zres[jj] = d;
  }

  #pragma unroll
  for (int jj = 0; jj < 2; ++jj) {
    const int col = 16 * (2 * wid + jj) + l15;
    const float bpv = bp[col];
    #pragma unroll
    for (int r = 0; r < 4; ++r) {
      int rr = grow0 + r; if (rr > 4999) rr = 4999;
      const int bb = rr / 2500, q = rr - bb * 2500;
      zres[jj][r] += bpv + skip[((size_t)(bb * 128 + col)) * 2500 + q];
    }
  }

  {
    float sum[4], sq[4];
    #pragma unroll
    for (int r = 0; r < 4; ++r) {
      sum[r] = zres[0][r] + zres[1][r];
      sq[r]  = zres[0][r] * zres[0][r] + zres[1][r] * zres[1][r];
    }
    #pragma unroll
    for (int r = 0; r < 4; ++r) {
      #pragma unroll
      for (int off = 1; off < 16; off <<= 1) {
        sum[r] += __shfl_xor(sum[r], off);
        sq[r]  += __shfl_xor(sq[r], off);
      }
    }
    if (l15 == 0) {
      float4 s0 = {sum[0], sq[0], sum[1], sq[1]};
      float4 s1 = {sum[2], sq[2], sum[3], sq[3]};
      *(float4*)&stat1[wid][4 * g][0]     = s0;
      *(float4*)&stat1[wid][4 * g + 2][0] = s1;
    }
  }
  __syncthreads();

  float mean[4], rstd[4];
  #pragma unroll
  for (int r = 0; r < 4; ++r) {
    float S = 0.f, S2 = 0.f;
    #pragma unroll
    for (int w2 = 0; w2 < 4; ++w2) {
      S  += stat1[w2][4 * g + r][0];
      S2 += stat1[w2][4 * g + r][1];
    }
    mean[r] = S * (1.f / 128.f);
    rstd[r] = rsqrtf(S2 * (1.f / 128.f) - mean[r] * mean[r] + 1e-5f);
  }

  #pragma unroll
  for (int jj = 0; jj < 2; ++jj) {
    const int col = 16 * (2 * wid + jj) + l15;
    const float g1 = ln1_g[col], bv1 = ln1_b[col];
    #pragma unroll
    for (int r = 0; r < 4; ++r) {
      const float vv = (zres[jj][r] - mean[r]) * rstd[r] * g1 + bv1;
      zres[jj][r] = vv;
      zl[4 * g + r][col] = f2b(vv);
    }
  }
  __syncthreads();

  short8v zA[4];
  #pragma unroll
  for (int c = 0; c < 4; ++c)
    zA[c] = *(const short8v*)&zl[l15][32 * c + 8 * g];
  #pragma unroll
  for (int jj = 0; jj < 4; ++jj) {
    const int j = 4 * wid + jj;
    f32x4 d = {0.f, 0.f, 0.f, 0.f};
    #pragma unroll
    for (int c = 0; c < 4; ++c) {
      const short8v wf = *(const short8v*)(w1k + (((c * 16 + j) * 64 + lane) << 3));
      d = __builtin_amdgcn_mfma_f32_16x16x32_bf16(zA[c], wf, d, 0, 0, 0);
    }
    const int col = 16 * j + l15;
    const float bv = b1[col];
    #pragma unroll
    for (int r = 0; r < 4; ++r) {
      const float x = d[r] + bv;
      hl[4 * g + r][col] = f2b(0.5f * x * (1.f + erff(x * 0.70710678118654752f)));
    }
  }
  __syncthreads();

  short8v hA[8];
  #pragma unroll
  for (int c = 0; c < 8; ++c)
    hA[c] = *(const short8v*)&hl[l15][32 * c + 8 * g];
  #pragma unroll
  for (int jj = 0; jj < 2; ++jj) {
    const int j = 2 * wid + jj;
    f32x4 d = {0.f, 0.f, 0.f, 0.f};
    #pragma unroll
    for (int c = 0; c < 8; ++c) {
      const short8v wf = *(const short8v*)(w2k + (((c * 8 + j) * 64 + lane) << 3));
      d = __builtin_amdgcn_mfma_f32_16x16x32_bf16(hA[c], wf, d, 0, 0, 0);
    }
    const int col = 16 * j + l15;
    const float bv = b2[col];
    #pragma unroll
    for (int r = 0; r < 4; ++r) zres[jj][r] += d[r] + bv;
  }

  {
    float sum[4], sq[4];
    #pragma unroll
    for (int r = 0; r < 4; ++r) {
      sum[r] = zres[0][r] + zres[1][r];
      sq[r]  = zres[0][r] * zres[0][r] + zres[1][r] * zres[1][r];
    }
    #pragma unroll
    for (int r = 0; r < 4; ++r) {
      #pragma unroll
      for (int off = 1; off < 16; off <<= 1) {
        sum[r] += __shfl_xor(sum[r], off);
        sq[r]  += __shfl_xor(sq[r], off);
      }
    }
    if (l15 == 0) {
      float4 s0 = {sum[0], sq[0], sum[1], sq[1]};
      float4 s1 = {sum[2], sq[2], sum[3], sq[3]};
      *(float4*)&stat2[wid][4 * g][0]     = s0;
      *(float4*)&stat2[wid][4 * g + 2][0] = s1;
    }
  }
  __syncthreads();

  float mean2[4], rstd2[4];
  #pragma unroll
  for (int r = 0; r < 4; ++r) {
    float S = 0.f, S2 = 0.f;
    #pragma unroll
    for (int w2 = 0; w2 < 4; ++w2) {
      S  += stat2[w2][4 * g + r][0];
      S2 += stat2[w2][4 * g + r][1];
    }
    mean2[r] = S * (1.f / 128.f);
    rstd2[r] = rsqrtf(S2 * (1.f / 128.f) - mean2[r] * mean2[r] + 1e-5f);
  }

  if (grow0 + 3 <= 4999) {
    const int bb = grow0 / 2500, q0 = grow0 - bb * 2500;
    #pragma unroll
    for (int jj = 0; jj < 2; ++jj) {
      const int col = 16 * (2 * wid + jj) + l15;
      const float g2 = ln2_g[col], bv2 = ln2_b[col];
      float4 o;
      o.x = (zres[jj][0] - mean2[0]) * rstd2[0] * g2 + bv2;
      o.y = (zres[jj][1] - mean2[1]) * rstd2[1] * g2 + bv2;
      o.z = (zres[jj][2] - mean2[2]) * rstd2[2] * g2 + bv2;
      o.w = (zres[jj][3] - mean2[3]) * rstd2[3] * g2 + bv2;
      *(float4*)(out + ((size_t)(bb * 128 + col)) * 2500 + q0) = o;
    }
  }
}

extern "C" void kernel_launch(void* const* d_in, const int* in_sizes, int n_in,
                              void* d_out, int out_size, void* d_ws, size_t ws_size,
                              hipStream_t stream)
{
  const float* q     = (const float*)d_in[0];
  const float* k     = (const float*)d_in[1];
  const float* v     = (const float*)d_in[2];
  const float* skip  = (const float*)d_in[3];
  const float* lnq_g = (const float*)d_in[4];
  const float* lnq_b = (const float*)d_in[5];
  const float* wq    = (const float*)d_in[6];
  const float* bq    = (const float*)d_in[7];
  const float* lnk_g = (const float*)d_in[8];
  const float* lnk_b = (const float*)d_in[9];
  const float* wk    = (const float*)d_in[10];
  const float* bk    = (const float*)d_in[11];
  const float* lnv_g = (const float*)d_in[12];
  const float* lnv_b = (const float*)d_in[13];
  const float* wv    = (const float*)d_in[14];
  const float* bv    = (const float*)d_in[15];
  const float* wp    = (const float*)d_in[16];
  const float* bp    = (const float*)d_in[17];
  const float* ln1_g = (const float*)d_in[18];
  const float* ln1_b = (const float*)d_in[19];
  const float* w1    = (const float*)d_in[20];
  const float* b1    = (const float*)d_in[21];
  const float* w2    = (const float*)d_in[22];
  const float* b2    = (const float*)d_in[23];
  const float* ln2_g = (const float*)d_in[24];
  const float* ln2_b = (const float*)d_in[25];

  unsigned short* kpb = (unsigned short*)d_ws;         // 655360
  unsigned short* vtb = kpb + 655360;                  // 655360
  unsigned short* qsb = vtb + 655360;                  // 640000
  unsigned short* wpk = qsb + 640000;                  // 16384
  unsigned short* w1k = wpk + 16384;                   // 32768
  unsigned short* w2k = w1k + 32768;                   // 32768
  unsigned short* wqk = w2k + 32768;                   // 16384
  unsigned short* wkk = wqk + 16384;                   // 16384
  unsigned short* wvk = wkk + 16384;                   // 16384
  float* pl = (float*)(wvk + 16384);                   // 2*4*8*2500 = 160000 floats
  unsigned short* pacc = (unsigned short*)(pl + 160000); // 160000*32 bf16 shorts

  setup_kernel<<<dim3(130), dim3(256), 0, stream>>>(wp, w1, w2, wq, wk, wv,
                                                    wpk, w1k, w2k, wqk, wkk, wvk,
                                                    kpb, vtb);
  proj_kernel<<<dim3(237), dim3(256), 0, stream>>>(
      k, v, lnk_g, lnk_b, wkk, bk, lnv_g, lnv_b, wvk, bv, kpb, vtb,
      q, lnq_g, lnq_b, wqk, bq, qsb);
  attn_kernel<<<dim3(640), dim3(256), 0, stream>>>(qsb, kpb, vtb, pl, pacc);
  tail_kernel<<<dim3(313), dim3(256), 0, stream>>>(
      pl, pacc, skip, wpk, bp, ln1_g, ln1_b, w1k, b1, w2k, b2, ln2_g, ln2_b, (float*)d_out);
}